// Round 12
// baseline (478.218 us; speedup 1.0000x reference)
//
#include <hip/hip_runtime.h>
#include <stdint.h>

#define T_TOK 8192
#define HD 1024
#define NE 8
#define FD 4096
#define RALLOC 18432
#define G1 1152
#define G2 384
#define NKT1 16
#define GATE_BLOCKS 2048

typedef __attribute__((ext_vector_type(8))) short bf16x8;
typedef __attribute__((ext_vector_type(4))) float f32x4;
typedef __attribute__((ext_vector_type(4))) short s16x4;

__device__ __forceinline__ unsigned short f2bf(float f) {
  unsigned u = __builtin_bit_cast(unsigned, f);
  u += 0x7fffu + ((u >> 16) & 1u);
  return (unsigned short)(u >> 16);
}

__device__ __forceinline__ void gld_lds16(const void* g, void* l) {
  __builtin_amdgcn_global_load_lds(
      (const __attribute__((address_space(1))) void*)g,
      (__attribute__((address_space(3))) void*)l, 16, 0, 0);
}

// ---------------- prep: fused weight transpose (blocks 0..16383) + gating (16384..18431) ----------------
__global__ __launch_bounds__(256) void k_prep(const float* __restrict__ w1,
                                              const float* __restrict__ w2,
                                              unsigned short* __restrict__ w1t,
                                              unsigned short* __restrict__ w2t,
                                              const float* __restrict__ x,
                                              const float* __restrict__ gw,
                                              int* __restrict__ toke,
                                              float* __restrict__ tokw,
                                              int* __restrict__ counts8,
                                              double* __restrict__ part,
                                              unsigned short* __restrict__ xbf) {
  __shared__ char smem[33056];
  const int i = blockIdx.x;
  const int tid = threadIdx.x;
  if (i < 16384) {
    // ---- transpose + cvt: f32 [R][C] -> bf16 [C][R] ----
    unsigned short* tile = (unsigned short*)smem;   // 64*80 ushort = 10240 B
    const float* src;
    unsigned short* dst;
    int R, C, r0, c0;
    if (i < 8192) {
      const int e = i >> 10, rem = i & 1023;
      R = HD; C = FD; r0 = (rem >> 6) << 6; c0 = (rem & 63) << 6;
      src = w1 + (size_t)e * R * C; dst = w1t + (size_t)e * R * C;
    } else {
      const int e = (i - 8192) >> 10, rem = (i - 8192) & 1023;
      R = FD; C = HD; r0 = (rem >> 4) << 6; c0 = (rem & 15) << 6;
      src = w2 + (size_t)e * R * C; dst = w2t + (size_t)e * R * C;
    }
    {
      const int r = tid >> 2, cg = (tid & 3) * 16;
      #pragma unroll
      for (int m = 0; m < 4; ++m) {
        float4 v = *(const float4*)(src + (size_t)(r0 + r) * C + c0 + cg + 4 * m);
        s16x4 pv;
        pv[0] = (short)f2bf(v.x); pv[1] = (short)f2bf(v.y);
        pv[2] = (short)f2bf(v.z); pv[3] = (short)f2bf(v.w);
        *(s16x4*)&tile[r * 80 + cg + 4 * m] = pv;
      }
    }
    __syncthreads();
    {
      const int c = tid >> 2, rg = (tid & 3) * 16;
      bf16x8 v0, v1;
      #pragma unroll
      for (int j = 0; j < 8; ++j) v0[j] = (short)tile[(rg + j) * 80 + c];
      #pragma unroll
      for (int j = 0; j < 8; ++j) v1[j] = (short)tile[(rg + 8 + j) * 80 + c];
      unsigned short* dp = dst + (size_t)(c0 + c) * R + r0 + rg;
      *(bf16x8*)dp = v0;
      *(bf16x8*)(dp + 8) = v1;
    }
  } else {
    // ---- gating: wave per token (4 tokens/block), gwT in LDS, f64 accum ----
    float* gwT = (float*)smem;                       // 32768 B
    double (*sp)[8] = (double(*)[8])(smem + 32768);  // 4*8*8 = 256 B
    int* scnt = (int*)(smem + 33024);                // 32 B
    const int gb = i - 16384;
    const int lane = tid & 63;
    const int w = tid >> 6;
    if (tid < 8) scnt[tid] = 0;
    #pragma unroll
    for (int rep = 0; rep < 32; ++rep) {
      int idx = rep * 256 + tid;
      gwT[(idx & 7) * 1024 + (idx >> 3)] = gw[idx];
    }
    __syncthreads();

    const int t = gb * 4 + w;
    double acc[8];
    #pragma unroll
    for (int e = 0; e < 8; ++e) acc[e] = 0.0;
    const float* xr = x + (size_t)t * HD;
    unsigned short* xbr = xbf + (size_t)t * HD;
    #pragma unroll
    for (int j = 0; j < 4; ++j) {
      const int hh = j * 256 + lane * 4;
      float4 xv = *(const float4*)(xr + hh);
      s16x4 pv;
      pv[0] = (short)f2bf(xv.x); pv[1] = (short)f2bf(xv.y);
      pv[2] = (short)f2bf(xv.z); pv[3] = (short)f2bf(xv.w);
      *(s16x4*)(xbr + hh) = pv;
      #pragma unroll
      for (int e = 0; e < 8; ++e) {
        float4 gv = *(const float4*)(gwT + e * 1024 + hh);
        acc[e] += (double)xv.x * (double)gv.x;
        acc[e] += (double)xv.y * (double)gv.y;
        acc[e] += (double)xv.z * (double)gv.z;
        acc[e] += (double)xv.w * (double)gv.w;
      }
    }
    for (int off = 32; off > 0; off >>= 1) {
      #pragma unroll
      for (int e = 0; e < 8; ++e) acc[e] += __shfl_xor(acc[e], off, 64);
    }
    double m = acc[0];
    #pragma unroll
    for (int e = 1; e < 8; ++e) m = fmax(m, acc[e]);
    double p[8], ssum = 0.0;
    #pragma unroll
    for (int e = 0; e < 8; ++e) { p[e] = exp(acc[e] - m); ssum += p[e]; }
    double inv = 1.0 / ssum;
    #pragma unroll
    for (int e = 0; e < 8; ++e) p[e] *= inv;
    int e0 = 0;
    #pragma unroll
    for (int e = 1; e < 8; ++e) if (p[e] > p[e0]) e0 = e;
    int e1 = (e0 == 0) ? 1 : 0;
    #pragma unroll
    for (int e = 0; e < 8; ++e) if (e != e0 && p[e] > p[e1]) e1 = e;
    if (lane == 0) {
      double z = exp(p[e1] - p[e0]);   // <= 1
      double w0 = 1.0 / (1.0 + z);
      toke[2 * t] = e0; toke[2 * t + 1] = e1;
      tokw[2 * t] = (float)w0; tokw[2 * t + 1] = (float)(z / (1.0 + z));
      atomicAdd(&scnt[e0], 1);
      atomicAdd(&scnt[e1], 1);
      #pragma unroll
      for (int e = 0; e < 8; ++e) sp[w][e] = p[e];
    }
    __syncthreads();
    if (tid < 8) {
      double s = 0.0;
      #pragma unroll
      for (int q = 0; q < 4; ++q) s += sp[q][tid];
      part[(size_t)gb * 8 + tid] = s;
      counts8[(size_t)gb * 8 + tid] = scnt[tid];
    }
  }
}

// ---------------- scan: offsets (256-padded), loss, padding fill ----------------
__global__ __launch_bounds__(256) void k_scan(const int* __restrict__ counts8,
                                              int* __restrict__ offs,
                                              int* __restrict__ cursors,
                                              const double* __restrict__ part,
                                              float* __restrict__ loss_out,
                                              int* __restrict__ rowmap,
                                              float* __restrict__ roww) {
  __shared__ double su[8];
  __shared__ int soffs[9];
  __shared__ int scnt[8];
  const int tid = threadIdx.x;
  const int e = tid >> 5, sub = tid & 31;
  double s = 0.0;
  int c = 0;
  for (int b = sub; b < GATE_BLOCKS; b += 32) {
    s += part[(size_t)b * 8 + e];
    c += counts8[(size_t)b * 8 + e];
  }
  for (int off = 16; off > 0; off >>= 1) {
    s += __shfl_xor(s, off, 64);
    c += __shfl_xor(c, off, 64);
  }
  if (sub == 0) { su[e] = s; scnt[e] = c; }
  __syncthreads();
  if (tid == 0) {
    int o = 0;
    for (int i = 0; i < 8; ++i) {
      soffs[i] = o; offs[i] = o; cursors[i * 16] = o;
      o += ((scnt[i] + 255) >> 8) << 8;
    }
    soffs[8] = o; offs[8] = o;
    double u[8], mx = -1e300;
    for (int i = 0; i < 8; ++i) { u[i] = su[i] / 8192.0; mx = fmax(mx, u[i]); }
    double se = 0.0;
    for (int i = 0; i < 8; ++i) se += exp(u[i] - mx);
    double lse = mx + log(se);
    double kl = 0.0;
    const double lu = log(0.125);
    for (int i = 0; i < 8; ++i) kl += 0.125 * (lu - (u[i] - lse));
    kl /= 8.0;
    loss_out[0] = (float)(0.01 * kl);
  }
  __syncthreads();
  for (int i = 0; i < 8; ++i) {
    int s0 = soffs[i] + scnt[i];
    int en = soffs[i + 1];
    for (int k = s0 + tid; k < en; k += 256) { rowmap[k] = 2 * T_TOK; roww[k] = 0.f; }
  }
}

// ---------------- scatter: rowmap entries encode 2*t+k; cursors line-padded ----------------
__global__ __launch_bounds__(256) void k_scatter(const int* __restrict__ toke,
                                                 const float* __restrict__ tokw,
                                                 int* __restrict__ cursors,
                                                 int* __restrict__ rowmap,
                                                 float* __restrict__ roww) {
  const int t = blockIdx.x * 256 + threadIdx.x;
  const int lane = threadIdx.x & 63;
  #pragma unroll
  for (int k = 0; k < 2; ++k) {
    int e = toke[2 * t + k];
    float wv = tokw[2 * t + k];
    for (int ex = 0; ex < 8; ++ex) {
      unsigned long long mask = __ballot(e == ex);
      if (e == ex) {
        int leader = __ffsll((unsigned long long)mask) - 1;
        int rank = __popcll(mask & ((1ull << lane) - 1ull));
        int base = 0;
        if (lane == leader) base = atomicAdd(&cursors[ex * 16], __popcll(mask));
        base = __shfl(base, leader, 64);
        rowmap[base + rank] = 2 * t + k;
        roww[base + rank] = wv;
      }
    }
  }
}

// ======== 256x256 GEMM machinery: 2-phase/K-tile, 32-MFMA clusters, counted vmcnt ========
#define RDA(buf, mh) do { _Pragma("unroll") for (int m_ = 0; m_ < 4; ++m_) { \
  af[m_][0] = *(const bf16x8*)(lds + (buf) * 65536 + wmOff + (mh) * 8192 + aoff[m_][0]); \
  af[m_][1] = *(const bf16x8*)(lds + (buf) * 65536 + wmOff + (mh) * 8192 + aoff[m_][1]); } } while (0)

#define RDB(buf, nh, B) do { _Pragma("unroll") for (int nf_ = 0; nf_ < 2; ++nf_) { \
  B[nf_][0] = *(const bf16x8*)(lds + (buf) * 65536 + wnOff + (nh) * 4096 + boff[nf_][0]); \
  B[nf_][1] = *(const bf16x8*)(lds + (buf) * 65536 + wnOff + (nh) * 4096 + boff[nf_][1]); } } while (0)

#define MMA(mh, nh, B) do { _Pragma("unroll") for (int m_ = 0; m_ < 4; ++m_) \
  _Pragma("unroll") for (int nf_ = 0; nf_ < 2; ++nf_) \
  _Pragma("unroll") for (int kh_ = 0; kh_ < 2; ++kh_) \
    acc[(mh) * 4 + m_][(nh) * 2 + nf_] = __builtin_amdgcn_mfma_f32_16x16x32_bf16( \
        af[m_][kh_], B[nf_][kh_], acc[(mh) * 4 + m_][(nh) * 2 + nf_], 0, 0, 0); } while (0)

#define SYNC_PRE() do { __builtin_amdgcn_sched_barrier(0); __builtin_amdgcn_s_barrier(); \
  asm volatile("s_waitcnt lgkmcnt(0)" ::: "memory"); __builtin_amdgcn_sched_barrier(0); \
  __builtin_amdgcn_s_setprio(1); } while (0)

#define SYNC_POST() do { __builtin_amdgcn_s_setprio(0); __builtin_amdgcn_sched_barrier(0); \
  __builtin_amdgcn_s_barrier(); __builtin_amdgcn_sched_barrier(0); } while (0)

#define SYNC_POST_VM() do { __builtin_amdgcn_s_setprio(0); __builtin_amdgcn_sched_barrier(0); \
  asm volatile("s_waitcnt vmcnt(4)" ::: "memory"); __builtin_amdgcn_sched_barrier(0); \
  __builtin_amdgcn_s_barrier(); __builtin_amdgcn_sched_barrier(0); } while (0)

#define FRAG_OFFSETS256() \
  int aoff[4][2], boff[2][2]; \
  { \
    const int kg = (lane >> 4) << 4; \
    _Pragma("unroll") \
    for (int m = 0; m < 4; ++m) { \
      int r = m * 16 + (lane & 15); \
      _Pragma("unroll") \
      for (int kh = 0; kh < 2; ++kh) \
        aoff[m][kh] = r * 128 + ((kh * 64 + kg) ^ ((r & 7) << 4)); \
    } \
    _Pragma("unroll") \
    for (int nf = 0; nf < 2; ++nf) { \
      int r = (wn & 1) * 64 + nf * 16 + (lane & 15); \
      _Pragma("unroll") \
      for (int kh = 0; kh < 2; ++kh) \
        boff[nf][kh] = r * 128 + ((kh * 64 + kg) ^ ((r & 7) << 4)); \
    } \
  }

// ---------------- GEMM1: h = relu(gather(x_bf) @ w1t^T + b1), bf16 out ----------------
// XCD map: contiguous balanced runs of row-tiles per XCD (runtime ntr), nb fastest.
__global__ __launch_bounds__(512, 2) void k_gemm1(const unsigned short* __restrict__ xbf,
                                                  const unsigned short* __restrict__ w1t,
                                                  const float* __restrict__ b1,
                                                  const int* __restrict__ rowmap,
                                                  const int* __restrict__ offs,
                                                  unsigned short* __restrict__ hbuf) {
  __shared__ char lds[131072];
  const int id = blockIdx.x;
  const int xcd = id & 7, j = id >> 3;      // j in 0..143
  const int lrt = j >> 4, nb = j & 15;
  const int ntr = offs[8] >> 8;             // valid row-tiles (<= 72)
  const int q = ntr >> 3, r8 = ntr & 7;
  const int cnt = q + (xcd < r8 ? 1 : 0);
  if (lrt >= cnt) return;
  const int start = (xcd < r8) ? xcd * (q + 1) : r8 * (q + 1) + (xcd - r8) * q;
  const int rt = start + lrt;
  const int row0 = rt * 256;
  int e = 0;
  #pragma unroll
  for (int i = 1; i < 8; ++i) if (row0 >= offs[i]) e = i;
  const int n0 = nb * 256;
  const int tid = threadIdx.x;
  const int lane = tid & 63;
  const int wid = tid >> 6;
  const int wm = wid >> 2, wn = wid & 3;

  const int rl = tid >> 3;
  const int cbs = ((tid & 7) << 4) ^ ((rl & 7) << 4);
  const char* pA[2][2];
  #pragma unroll
  for (int h = 0; h < 2; ++h)
    #pragma unroll
    for (int l = 0; l < 2; ++l) {
      int tok = rowmap[row0 + h * 128 + l * 64 + rl] >> 1;
      pA[h][l] = (const char*)xbf + (size_t)tok * 2048 + cbs;
    }
  const char* pB00 = (const char*)w1t + (size_t)e * ((size_t)FD * HD * 2) +
                     (size_t)(n0 + rl) * 2048 + cbs;
  const int stw = wid * 1024;

#define STA1(buf, h, kt) do { \
  gld_lds16(pA[h][0] + (size_t)(kt) * 128, lds + (buf) * 65536 + (h) * 16384 + stw); \
  gld_lds16(pA[h][1] + (size_t)(kt) * 128, lds + (buf) * 65536 + (h) * 16384 + 8192 + stw); } while (0)
#define STB1(buf, h, kt) do { \
  gld_lds16(pB00 + (size_t)(h) * 128 * 2048 + (size_t)(kt) * 128, \
            lds + (buf) * 65536 + 32768 + (h) * 16384 + stw); \
  gld_lds16(pB00 + ((size_t)(h) * 128 + 64) * 2048 + (size_t)(kt) * 128, \
            lds + (buf) * 65536 + 32768 + (h) * 16384 + 8192 + stw); } while (0)

  FRAG_OFFSETS256();
  const int wmOff = wm * 16384;
  const int wnOff = 32768 + (wn >> 1) * 16384;

  f32x4 acc[8][4];
  #pragma unroll
  for (int a = 0; a < 8; ++a)
    #pragma unroll
    for (int b = 0; b < 4; ++b) acc[a][b] = (f32x4){0.f, 0.f, 0.f, 0.f};
  bf16x8 af[4][2], b0r[2][2], b1r[2][2];

  STA1(0, 0, 0); STA1(0, 1, 0); STB1(0, 0, 0); STB1(0, 1, 0);
  STB1(1, 0, 1); STB1(1, 1, 1);
  asm volatile("s_waitcnt vmcnt(4)" ::: "memory");
  __builtin_amdgcn_sched_barrier(0);
  __builtin_amdgcn_s_barrier();
  __builtin_amdgcn_sched_barrier(0);

  #pragma unroll 1
  for (int i = 0; i < NKT1 / 2; ++i) {
    const int k1 = 2 * i + 1, k2 = 2 * i + 2, k3 = 2 * i + 3;
    RDA(0, 0); RDB(0, 0, b0r); RDB(0, 1, b1r); STA1(1, 0, k1); STA1(1, 1, k1);
      SYNC_PRE(); MMA(0, 0, b0r); MMA(0, 1, b1r); SYNC_POST();
    RDA(0, 1); STB1(0, 0, k2); STB1(0, 1, k2);
      SYNC_PRE(); MMA(1, 0, b0r); MMA(1, 1, b1r); SYNC_POST_VM();
    RDA(1, 0); RDB(1, 0, b0r); RDB(1, 1, b1r); STA1(0, 0, k2); STA1(0, 1, k2);
      SYNC_PRE(); MMA(0, 0, b0r); MMA(0, 1, b1r); SYNC_POST();
    RDA(1, 1); STB1(1, 0, k3); STB1(1, 1, k3);
      SYNC_PRE(); MMA(1, 0, b0r); MMA(1, 1, b1r); SYNC_POST_VM();
  }

  asm volatile("s_waitcnt vmcnt(0)" ::: "memory");
  __builtin_amdgcn_sched_barrier(0);
  __syncthreads();
  // bias + relu -> LDS bf16 [256][512B] swizzled -> coalesced store
  #pragma unroll
  for (int na = 0; na < 4; ++na) {
    int c = wn * 64 + (na >> 1) * 32 + (na & 1) * 16 + (lane & 15);
    float bias = b1[(size_t)e * FD + n0 + c];
    #pragma unroll
    for (int ma = 0; ma < 8; ++ma) {
      #pragma unroll
      for (int j2 = 0; j2 < 4; ++j2) {
        int r = wm * 128 + (ma >> 2) * 64 + (ma & 3) * 16 + ((lane >> 4) << 2) + j2;
        float v = fmaxf(acc[ma][na][j2] + bias, 0.f);
        *(unsigned short*)(lds + r * 512 + ((c * 2) ^ ((r & 7) << 4))) = f2bf(v);
      }
    }
  }
  __syncthreads();
  #pragma unroll
  for (int s = 0; s < 16; ++s) {
    int flat = s * 512 + tid;
    int r = flat >> 5, ch = flat & 31;
    bf16x8 v = *(const bf16x8*)(lds + r * 512 + ((ch * 16) ^ ((r & 7) << 4)));
    *(bf16x8*)((char*)hbuf + (size_t)(row0 + r) * 8192 + (size_t)n0 * 2 + ch * 16) = v;
  }
#undef STA1
#undef STB1
}

// ---------------- GEMM2: fulls -> out2; tail quarter-K jobs -> psplit ----------------
__global__ __launch_bounds__(512, 2) void k_gemm2(const unsigned short* __restrict__ hbuf,
                                                  const unsigned short* __restrict__ w2t,
                                                  const float* __restrict__ b2,
                                                  const int* __restrict__ rowmap,
                                                  const float* __restrict__ roww,
                                                  const int* __restrict__ offs,
                                                  float* __restrict__ out2,
                                                  float* __restrict__ psplit) {
  __shared__ char lds[131072];
  const int id = blockIdx.x;
  int bx, by, kt0, niter, jj = -1;
  if (id < 256) {
    const int sid = (id & 7) * 32 + (id >> 3);   // bijective over 256
    bx = sid & 3; by = sid >> 2;                 // by < 64: always valid
    kt0 = 0; niter = 32;
  } else {
    const int jid = id - 256;
    const int q = (jid & 7) * 16 + (jid >> 3);   // bijective over 128
    const int t = 256 + (q >> 2);
    const int nT2 = (offs[8] >> 8) * 4;
    if (t >= nT2) return;
    bx = t & 3; by = t >> 2;
    kt0 = (q & 3) * 16; niter = 8;
    jj = q;
  }
  const int row0 = by * 256;
  int e = 0;
  #pragma unroll
  for (int i = 1; i < 8; ++i) if (row0 >= offs[i]) e = i;
  const int n0 = bx * 256;
  const int tid = threadIdx.x;
  const int lane = tid & 63;
  const int wid = tid >> 6;
  const int wm = wid >> 2, wn = wid & 3;

  const int rl = tid >> 3;
  const int cbs = ((tid & 7) << 4) ^ ((rl & 7) << 4);
  const char* pA00 = (const char*)hbuf + (size_t)(row0 + rl) * 8192 + cbs;
  const char* pB00 = (const char*)w2t + (size_t)e * ((size_t)HD * FD * 2) +
                     (size_t)(n0 + rl) * 8192 + cbs;
  const int stw = wid * 1024;

#define STA2(buf, h, kt) do { \
  gld_lds16(pA00 + (size_t)(h) * 128 * 8192 + (size_t)(kt) * 128, \
            lds + (buf) * 65536 + (h) * 16384 + stw); \
  gld_lds16(pA00 + ((size_t)(h) * 128 + 64) * 8192 + (size_t)(kt) * 128, \
            lds + (buf) * 65536 + (h) * 16384 + 8192 + stw); } while (0)
#define STB2(buf, h, kt) do { \
  gld_lds16(pB00 + (size_t)(h) * 128 * 8192 + (size_t)(kt) * 128, \
            lds + (buf) * 65536 + 32768 + (h) * 16384 + stw); \
  gld_lds16(pB00 + ((size_t)(h) * 128 + 64) * 8192 + (size_t)(kt) * 128, \
            lds + (buf) * 65536 + 32768 + (h) * 16384 + 8192 + stw); } while (0)

  FRAG_OFFSETS256();
  const int wmOff = wm * 16384;
  const int wnOff = 32768 + (wn >> 1) * 16384;

  f32x4 acc[8][4];
  #pragma unroll
  for (int a = 0; a < 8; ++a)
    #pragma unroll
    for (int b = 0; b < 4; ++b) acc[a][b] = (f32x4){0.f, 0.f, 0.f, 0.f};
  bf16x8 af[4][2], b0r[2][2], b1r[2][2];

  STA2(0, 0, kt0); STA2(0, 1, kt0); STB2(0, 0, kt0); STB2(0, 1, kt0);
  STB2(1, 0, kt0 + 1); STB2(1, 1, kt0 + 1);
  asm volatile("s_waitcnt vmcnt(4)" ::: "memory");
  __builtin_amdgcn_sched_barrier(0);
  __builtin_amdgcn_s_barrier();
  __builtin_amdgcn_sched_barrier(0);

  #pragma unroll 1
  for (int i = 0; i < niter; ++i) {
    const int k1 = kt0 + 2 * i + 1, k2 = kt0 + 2 * i + 2, k3 = kt0 + 2 * i + 3;
    RDA(0, 0); RDB(0, 0, b0r); RDB(0, 1, b1r); STA2(1, 0, k1); STA2(1, 1, k1);
      SYNC_PRE(); MMA(0, 0, b0r); MMA(0, 1, b1r); SYNC_POST();
    RDA(0, 1); STB2(0, 0, k2); STB2(0, 1, k2);
      SYNC_PRE(); MMA(1, 0, b0r); MMA(1, 1, b1r); SYNC_POST_VM();
    RDA(1, 0); RDB(1, 0, b0r); RDB(1, 1, b1r); STA2(0, 0, k2); STA2(0, 1, k2);
      SYNC_PRE(); MMA(0, 0, b0r); MMA(0, 1, b1r); SYNC_POST();
    RDA(1, 1); STB2(1, 0, k3); STB2(1, 1, k3);
      SYNC_PRE(); MMA(1, 0, b0r); MMA(1, 1, b1r); SYNC_POST_VM();
  }

  asm volatile("s_waitcnt vmcnt(0)" ::: "memory");
  __builtin_amdgcn_sched_barrier(0);
  if (jj < 0) {
    // full tile: bias + weight scale -> out2 slot rows (padding -> trash row)
    #pragma unroll
    for (int ma = 0; ma < 8; ++ma) {
      #pragma unroll
      for (int j2 = 0; j2 < 4; ++j2) {
        int r = wm * 128 + (ma >> 2) * 64 + (ma & 3) * 16 + ((lane >> 4) << 2) + j2;
        int rm = rowmap[row0 + r];
        float wr = roww[row0 + r];
        float* orow = out2 + (size_t)rm * 1024 + n0;
        #pragma unroll
        for (int na = 0; na < 4; ++na) {
          int c = wn * 64 + (na >> 1) * 32 + (na & 1) * 16 + (lane & 15);
          orow[c] = (acc[ma][na][j2] + b2[(size_t)e * HD + n0 + c]) * wr;
        }
      }
    }
  } else {
    // quarter job: raw partial sums -> psplit[jj][256][256]
    float* ps = psplit + (size_t)jj * 65536;
    #pragma unroll
    for (int ma = 0; ma < 8; ++ma) {
      #pragma unroll
      for (int j2 = 0; j2 < 4; ++j2) {
        int r = wm * 128 + (ma >> 2) * 64 + (ma & 3) * 16 + ((lane >> 4) << 2) + j2;
        #pragma unroll
        for (int na = 0; na < 4; ++na) {
          int c = wn * 64 + (na >> 1) * 32 + (na & 1) * 16 + (lane & 15);
          ps[r * 256 + c] = acc[ma][na][j2];
        }
      }
    }
  }
#undef STA2
#undef STB2
}

// ---------------- fix2: combine quarter partials of tail tiles into out2 ----------------
__global__ __launch_bounds__(512) void k_fix2(const float* __restrict__ psplit,
                                              const int* __restrict__ offs,
                                              const float* __restrict__ b2,
                                              const int* __restrict__ rowmap,
                                              const float* __restrict__ roww,
                                              float* __restrict__ out2) {
  const int nT2 = (offs[8] >> 8) * 4;
  const int t = 256 + blockIdx.x;
  if (t >= nT2) return;
  const int by = t >> 2, bx = t & 3;
  const int row0 = by * 256, n0 = bx * 256;
  int e = 0;
  #pragma unroll
  for (int i = 1; i < 8; ++i) if (row0 >= offs[i]) e = i;
  const float* ps = psplit + (size_t)blockIdx.x * 4 * 65536;
  const int cg = (threadIdx.x & 63) * 4;
  const int r0t = threadIdx.x >> 6;
  float4 bb = *(const float4*)(b2 + (size_t)e * HD + n0 + cg);
  for (int rr = 0; rr < 32; ++rr) {
    int r = rr * 8 + r0t;
    int rm = rowmap[row0 + r];
    float wr = roww[row0 + r];
    float4 s0 = *(const float4*)(ps + 0 * 65536 + r * 256 + cg);
    float4 s1 = *(const float4*)(ps + 1 * 65536 + r * 256 + cg);
    float4 s2 = *(const float4*)(ps + 2 * 65536 + r * 256 + cg);
    float4 s3 = *(const float4*)(ps + 3 * 65536 + r * 256 + cg);
    float4 o;
    o.x = wr * (s0.x + s1.x + s2.x + s3.x + bb.x);
    o.y = wr * (s0.y + s1.y + s2.y + s3.y + bb.y);
    o.z = wr * (s0.z + s1.z + s2.z + s3.z + bb.z);
    o.w = wr * (s0.w + s1.w + s2.w + s3.w + bb.w);
    *(float4*)(out2 + (size_t)rm * 1024 + n0 + cg) = o;
  }
}

// ---------------- combine: out[t] = out2[2t] + out2[2t+1] ----------------
__global__ __launch_bounds__(256) void k_combine(const float* __restrict__ out2,
                                                 float* __restrict__ out) {
  const int t = blockIdx.x;
  const int i = threadIdx.x * 4;
  float4 a = *(const float4*)(out2 + (size_t)(2 * t) * 1024 + i);
  float4 b = *(const float4*)(out2 + (size_t)(2 * t + 1) * 1024 + i);
  float4 r;
  r.x = a.x + b.x; r.y = a.y + b.y; r.z = a.z + b.z; r.w = a.w + b.w;
  *(float4*)(out + (size_t)t * 1024 + i) = r;
}

extern "C" void kernel_launch(void* const* d_in, const int* in_sizes, int n_in,
                              void* d_out, int out_size, void* d_ws, size_t ws_size,
                              hipStream_t stream) {
  const float* x = (const float*)d_in[0];
  const float* gw = (const float*)d_in[1];
  const float* w1 = (const float*)d_in[2];
  const float* b1 = (const float*)d_in[3];
  const float* w2 = (const float*)d_in[4];
  const float* b2 = (const float*)d_in[5];
  float* out = (float*)d_out;

  char* ws = (char*)d_ws;
  size_t o = 0;
  unsigned short* w2t = (unsigned short*)(ws + o); o += (size_t)NE * HD * FD * 2;   // 64 MiB
  unsigned short* hbuf = (unsigned short*)(ws + o); o += (size_t)RALLOC * FD * 2;   // 144 MiB
  unsigned short* w1t = (unsigned short*)(ws + o);
  size_t w1t_off = o; o += (size_t)NE * FD * HD * 2;                                // 64 MiB
  unsigned short* xbf = (unsigned short*)(ws + o); o += (size_t)T_TOK * HD * 2;     // 16 MiB
  int* rowmap = (int*)(ws + o); o += (size_t)RALLOC * 4;
  float* roww = (float*)(ws + o); o += (size_t)RALLOC * 4;
  int* toke = (int*)(ws + o); o += (size_t)T_TOK * 2 * 4;
  float* tokw = (float*)(ws + o); o += (size_t)T_TOK * 2 * 4;
  double* part = (double*)(ws + o); o += (size_t)GATE_BLOCKS * 8 * 8;
  int* counts8 = (int*)(ws + o); o += (size_t)GATE_BLOCKS * 8 * 4;
  int* ctrl = (int*)(ws + o); o += 1024;
  int* offs = ctrl;            // 9 ints
  int* cursors = ctrl + 64;    // 8 cursors, stride 16 ints
  float* psplit = (float*)(ws + o); o += (size_t)128 * 65536 * 4;                   // 32 MiB
  // out2 aliases [w1t ∪ xbf] (both dead after gemm1): 64.004 MiB < 80 MiB
  float* out2 = (float*)(ws + w1t_off);

  k_prep<<<16384 + GATE_BLOCKS, 256, 0, stream>>>(w1, w2, w1t, w2t, x, gw, toke, tokw,
                                                  counts8, part, xbf);
  k_scan<<<1, 256, 0, stream>>>(counts8, offs, cursors, part, out + (size_t)T_TOK * HD,
                                rowmap, roww);
  k_scatter<<<T_TOK / 256, 256, 0, stream>>>(toke, tokw, cursors, rowmap, roww);
  k_gemm1<<<G1, 512, 0, stream>>>(xbf, w1t, b1, rowmap, offs, hbuf);
  k_gemm2<<<G2, 512, 0, stream>>>(hbuf, w2t, b2, rowmap, roww, offs, out2, psplit);
  k_fix2<<<32, 512, 0, stream>>>(psplit, offs, b2, rowmap, roww, out2);
  k_combine<<<T_TOK, 256, 0, stream>>>(out2, out);
}

// Round 13
// 476.247 us; speedup vs baseline: 1.0041x; 1.0041x over previous
//
#include <hip/hip_runtime.h>
#include <stdint.h>

#define T_TOK 8192
#define HD 1024
#define NE 8
#define FD 4096
#define RALLOC 18432
#define G1 1152
#define G2 384
#define NKT1 16
#define GATE_BLOCKS 2048

typedef __attribute__((ext_vector_type(8))) short bf16x8;
typedef __attribute__((ext_vector_type(4))) float f32x4;
typedef __attribute__((ext_vector_type(4))) short s16x4;

__device__ __forceinline__ unsigned short f2bf(float f) {
  unsigned u = __builtin_bit_cast(unsigned, f);
  u += 0x7fffu + ((u >> 16) & 1u);
  return (unsigned short)(u >> 16);
}

__device__ __forceinline__ void gld_lds16(const void* g, void* l) {
  __builtin_amdgcn_global_load_lds(
      (const __attribute__((address_space(1))) void*)g,
      (__attribute__((address_space(3))) void*)l, 16, 0, 0);
}

// ---------------- prep: fused weight transpose (blocks 0..16383) + gating (16384..18431) ----------------
__global__ __launch_bounds__(256) void k_prep(const float* __restrict__ w1,
                                              const float* __restrict__ w2,
                                              unsigned short* __restrict__ w1t,
                                              unsigned short* __restrict__ w2t,
                                              const float* __restrict__ x,
                                              const float* __restrict__ gw,
                                              int* __restrict__ toke,
                                              float* __restrict__ tokw,
                                              int* __restrict__ counts8,
                                              double* __restrict__ part,
                                              unsigned short* __restrict__ xbf) {
  __shared__ char smem[33056];
  const int i = blockIdx.x;
  const int tid = threadIdx.x;
  if (i < 16384) {
    // ---- transpose + cvt: f32 [R][C] -> bf16 [C][R] ----
    unsigned short* tile = (unsigned short*)smem;   // 64*80 ushort = 10240 B
    const float* src;
    unsigned short* dst;
    int R, C, r0, c0;
    if (i < 8192) {
      const int e = i >> 10, rem = i & 1023;
      R = HD; C = FD; r0 = (rem >> 6) << 6; c0 = (rem & 63) << 6;
      src = w1 + (size_t)e * R * C; dst = w1t + (size_t)e * R * C;
    } else {
      const int e = (i - 8192) >> 10, rem = (i - 8192) & 1023;
      R = FD; C = HD; r0 = (rem >> 4) << 6; c0 = (rem & 15) << 6;
      src = w2 + (size_t)e * R * C; dst = w2t + (size_t)e * R * C;
    }
    {
      const int r = tid >> 2, cg = (tid & 3) * 16;
      #pragma unroll
      for (int m = 0; m < 4; ++m) {
        float4 v = *(const float4*)(src + (size_t)(r0 + r) * C + c0 + cg + 4 * m);
        s16x4 pv;
        pv[0] = (short)f2bf(v.x); pv[1] = (short)f2bf(v.y);
        pv[2] = (short)f2bf(v.z); pv[3] = (short)f2bf(v.w);
        *(s16x4*)&tile[r * 80 + cg + 4 * m] = pv;
      }
    }
    __syncthreads();
    {
      const int c = tid >> 2, rg = (tid & 3) * 16;
      bf16x8 v0, v1;
      #pragma unroll
      for (int j = 0; j < 8; ++j) v0[j] = (short)tile[(rg + j) * 80 + c];
      #pragma unroll
      for (int j = 0; j < 8; ++j) v1[j] = (short)tile[(rg + 8 + j) * 80 + c];
      unsigned short* dp = dst + (size_t)(c0 + c) * R + r0 + rg;
      *(bf16x8*)dp = v0;
      *(bf16x8*)(dp + 8) = v1;
    }
  } else {
    // ---- gating: wave per token (4 tokens/block), gwT in LDS, f64 accum ----
    float* gwT = (float*)smem;                       // 32768 B
    double (*sp)[8] = (double(*)[8])(smem + 32768);  // 4*8*8 = 256 B
    int* scnt = (int*)(smem + 33024);                // 32 B
    const int gb = i - 16384;
    const int lane = tid & 63;
    const int w = tid >> 6;
    if (tid < 8) scnt[tid] = 0;
    #pragma unroll
    for (int rep = 0; rep < 32; ++rep) {
      int idx = rep * 256 + tid;
      gwT[(idx & 7) * 1024 + (idx >> 3)] = gw[idx];
    }
    __syncthreads();

    const int t = gb * 4 + w;
    double acc[8];
    #pragma unroll
    for (int e = 0; e < 8; ++e) acc[e] = 0.0;
    const float* xr = x + (size_t)t * HD;
    unsigned short* xbr = xbf + (size_t)t * HD;
    #pragma unroll
    for (int j = 0; j < 4; ++j) {
      const int hh = j * 256 + lane * 4;
      float4 xv = *(const float4*)(xr + hh);
      s16x4 pv;
      pv[0] = (short)f2bf(xv.x); pv[1] = (short)f2bf(xv.y);
      pv[2] = (short)f2bf(xv.z); pv[3] = (short)f2bf(xv.w);
      *(s16x4*)(xbr + hh) = pv;
      #pragma unroll
      for (int e = 0; e < 8; ++e) {
        float4 gv = *(const float4*)(gwT + e * 1024 + hh);
        acc[e] += (double)xv.x * (double)gv.x;
        acc[e] += (double)xv.y * (double)gv.y;
        acc[e] += (double)xv.z * (double)gv.z;
        acc[e] += (double)xv.w * (double)gv.w;
      }
    }
    for (int off = 32; off > 0; off >>= 1) {
      #pragma unroll
      for (int e = 0; e < 8; ++e) acc[e] += __shfl_xor(acc[e], off, 64);
    }
    double m = acc[0];
    #pragma unroll
    for (int e = 1; e < 8; ++e) m = fmax(m, acc[e]);
    double p[8], ssum = 0.0;
    #pragma unroll
    for (int e = 0; e < 8; ++e) { p[e] = exp(acc[e] - m); ssum += p[e]; }
    double inv = 1.0 / ssum;
    #pragma unroll
    for (int e = 0; e < 8; ++e) p[e] *= inv;
    int e0 = 0;
    #pragma unroll
    for (int e = 1; e < 8; ++e) if (p[e] > p[e0]) e0 = e;
    int e1 = (e0 == 0) ? 1 : 0;
    #pragma unroll
    for (int e = 0; e < 8; ++e) if (e != e0 && p[e] > p[e1]) e1 = e;
    if (lane == 0) {
      double z = exp(p[e1] - p[e0]);   // <= 1
      double w0 = 1.0 / (1.0 + z);
      toke[2 * t] = e0; toke[2 * t + 1] = e1;
      tokw[2 * t] = (float)w0; tokw[2 * t + 1] = (float)(z / (1.0 + z));
      atomicAdd(&scnt[e0], 1);
      atomicAdd(&scnt[e1], 1);
      #pragma unroll
      for (int e = 0; e < 8; ++e) sp[w][e] = p[e];
    }
    __syncthreads();
    if (tid < 8) {
      double s = 0.0;
      #pragma unroll
      for (int q = 0; q < 4; ++q) s += sp[q][tid];
      part[(size_t)gb * 8 + tid] = s;
      counts8[(size_t)gb * 8 + tid] = scnt[tid];
    }
  }
}

// ---------------- scan: offsets (256-padded), loss, padding fill ----------------
__global__ __launch_bounds__(256) void k_scan(const int* __restrict__ counts8,
                                              int* __restrict__ offs,
                                              int* __restrict__ cursors,
                                              const double* __restrict__ part,
                                              float* __restrict__ loss_out,
                                              int* __restrict__ rowmap,
                                              float* __restrict__ roww) {
  __shared__ double su[8];
  __shared__ int soffs[9];
  __shared__ int scnt[8];
  const int tid = threadIdx.x;
  const int e = tid >> 5, sub = tid & 31;
  double s = 0.0;
  int c = 0;
  for (int b = sub; b < GATE_BLOCKS; b += 32) {
    s += part[(size_t)b * 8 + e];
    c += counts8[(size_t)b * 8 + e];
  }
  for (int off = 16; off > 0; off >>= 1) {
    s += __shfl_xor(s, off, 64);
    c += __shfl_xor(c, off, 64);
  }
  if (sub == 0) { su[e] = s; scnt[e] = c; }
  __syncthreads();
  if (tid == 0) {
    int o = 0;
    for (int i = 0; i < 8; ++i) {
      soffs[i] = o; offs[i] = o; cursors[i * 16] = o;
      o += ((scnt[i] + 255) >> 8) << 8;
    }
    soffs[8] = o; offs[8] = o;
    double u[8], mx = -1e300;
    for (int i = 0; i < 8; ++i) { u[i] = su[i] / 8192.0; mx = fmax(mx, u[i]); }
    double se = 0.0;
    for (int i = 0; i < 8; ++i) se += exp(u[i] - mx);
    double lse = mx + log(se);
    double kl = 0.0;
    const double lu = log(0.125);
    for (int i = 0; i < 8; ++i) kl += 0.125 * (lu - (u[i] - lse));
    kl /= 8.0;
    loss_out[0] = (float)(0.01 * kl);
  }
  __syncthreads();
  for (int i = 0; i < 8; ++i) {
    int s0 = soffs[i] + scnt[i];
    int en = soffs[i + 1];
    for (int k = s0 + tid; k < en; k += 256) { rowmap[k] = 2 * T_TOK; roww[k] = 0.f; }
  }
}

// ---------------- scatter: rowmap entries encode 2*t+k; cursors line-padded ----------------
__global__ __launch_bounds__(256) void k_scatter(const int* __restrict__ toke,
                                                 const float* __restrict__ tokw,
                                                 int* __restrict__ cursors,
                                                 int* __restrict__ rowmap,
                                                 float* __restrict__ roww) {
  const int t = blockIdx.x * 256 + threadIdx.x;
  const int lane = threadIdx.x & 63;
  #pragma unroll
  for (int k = 0; k < 2; ++k) {
    int e = toke[2 * t + k];
    float wv = tokw[2 * t + k];
    for (int ex = 0; ex < 8; ++ex) {
      unsigned long long mask = __ballot(e == ex);
      if (e == ex) {
        int leader = __ffsll((unsigned long long)mask) - 1;
        int rank = __popcll(mask & ((1ull << lane) - 1ull));
        int base = 0;
        if (lane == leader) base = atomicAdd(&cursors[ex * 16], __popcll(mask));
        base = __shfl(base, leader, 64);
        rowmap[base + rank] = 2 * t + k;
        roww[base + rank] = wv;
      }
    }
  }
}

// ======== 256x256 8-phase GEMM machinery (R11-proven fine interleave) ========
#define RDA(buf, mh) do { _Pragma("unroll") for (int m_ = 0; m_ < 4; ++m_) { \
  af[m_][0] = *(const bf16x8*)(lds + (buf) * 65536 + wmOff + (mh) * 8192 + aoff[m_][0]); \
  af[m_][1] = *(const bf16x8*)(lds + (buf) * 65536 + wmOff + (mh) * 8192 + aoff[m_][1]); } } while (0)

#define RDB(buf, nh, B) do { _Pragma("unroll") for (int nf_ = 0; nf_ < 2; ++nf_) { \
  B[nf_][0] = *(const bf16x8*)(lds + (buf) * 65536 + wnOff + (nh) * 4096 + boff[nf_][0]); \
  B[nf_][1] = *(const bf16x8*)(lds + (buf) * 65536 + wnOff + (nh) * 4096 + boff[nf_][1]); } } while (0)

#define MMA(mh, nh, B) do { _Pragma("unroll") for (int m_ = 0; m_ < 4; ++m_) \
  _Pragma("unroll") for (int nf_ = 0; nf_ < 2; ++nf_) \
  _Pragma("unroll") for (int kh_ = 0; kh_ < 2; ++kh_) \
    acc[(mh) * 4 + m_][(nh) * 2 + nf_] = __builtin_amdgcn_mfma_f32_16x16x32_bf16( \
        af[m_][kh_], B[nf_][kh_], acc[(mh) * 4 + m_][(nh) * 2 + nf_], 0, 0, 0); } while (0)

#define SYNC_PRE() do { __builtin_amdgcn_sched_barrier(0); __builtin_amdgcn_s_barrier(); \
  asm volatile("s_waitcnt lgkmcnt(0)" ::: "memory"); __builtin_amdgcn_sched_barrier(0); \
  __builtin_amdgcn_s_setprio(1); } while (0)

#define SYNC_POST() do { __builtin_amdgcn_s_setprio(0); __builtin_amdgcn_sched_barrier(0); \
  __builtin_amdgcn_s_barrier(); __builtin_amdgcn_sched_barrier(0); } while (0)

#define SYNC_POST_VM() do { __builtin_amdgcn_s_setprio(0); __builtin_amdgcn_sched_barrier(0); \
  asm volatile("s_waitcnt vmcnt(4)" ::: "memory"); __builtin_amdgcn_sched_barrier(0); \
  __builtin_amdgcn_s_barrier(); __builtin_amdgcn_sched_barrier(0); } while (0)

#define FRAG_OFFSETS256() \
  int aoff[4][2], boff[2][2]; \
  { \
    const int kg = (lane >> 4) << 4; \
    _Pragma("unroll") \
    for (int m = 0; m < 4; ++m) { \
      int r = m * 16 + (lane & 15); \
      _Pragma("unroll") \
      for (int kh = 0; kh < 2; ++kh) \
        aoff[m][kh] = r * 128 + ((kh * 64 + kg) ^ ((r & 7) << 4)); \
    } \
    _Pragma("unroll") \
    for (int nf = 0; nf < 2; ++nf) { \
      int r = (wn & 1) * 64 + nf * 16 + (lane & 15); \
      _Pragma("unroll") \
      for (int kh = 0; kh < 2; ++kh) \
        boff[nf][kh] = r * 128 + ((kh * 64 + kg) ^ ((r & 7) << 4)); \
    } \
  }

// ---------------- GEMM1: h = relu(gather(x_bf) @ w1t^T + b1), bf16 out ----------------
// XCD map: contiguous balanced runs of row-tiles per XCD (runtime ntr), nb fastest.
__global__ __launch_bounds__(512, 2) void k_gemm1(const unsigned short* __restrict__ xbf,
                                                  const unsigned short* __restrict__ w1t,
                                                  const float* __restrict__ b1,
                                                  const int* __restrict__ rowmap,
                                                  const int* __restrict__ offs,
                                                  unsigned short* __restrict__ hbuf) {
  __shared__ char lds[131072];
  const int id = blockIdx.x;
  const int xcd = id & 7, j = id >> 3;      // j in 0..143
  const int lrt = j >> 4, nb = j & 15;
  const int ntr = offs[8] >> 8;             // valid row-tiles (<= 72)
  const int q = ntr >> 3, r8 = ntr & 7;
  const int cnt = q + (xcd < r8 ? 1 : 0);
  if (lrt >= cnt) return;
  const int start = (xcd < r8) ? xcd * (q + 1) : r8 * (q + 1) + (xcd - r8) * q;
  const int rt = start + lrt;
  const int row0 = rt * 256;
  int e = 0;
  #pragma unroll
  for (int i = 1; i < 8; ++i) if (row0 >= offs[i]) e = i;
  const int n0 = nb * 256;
  const int tid = threadIdx.x;
  const int lane = tid & 63;
  const int wid = tid >> 6;
  const int wm = wid >> 2, wn = wid & 3;

  const int rl = tid >> 3;
  const int cbs = ((tid & 7) << 4) ^ ((rl & 7) << 4);
  const char* pA[2][2];
  #pragma unroll
  for (int h = 0; h < 2; ++h)
    #pragma unroll
    for (int l = 0; l < 2; ++l) {
      int tok = rowmap[row0 + h * 128 + l * 64 + rl] >> 1;
      pA[h][l] = (const char*)xbf + (size_t)tok * 2048 + cbs;
    }
  const char* pB00 = (const char*)w1t + (size_t)e * ((size_t)FD * HD * 2) +
                     (size_t)(n0 + rl) * 2048 + cbs;
  const int stw = wid * 1024;

#define STA1(buf, h, kt) do { \
  gld_lds16(pA[h][0] + (size_t)(kt) * 128, lds + (buf) * 65536 + (h) * 16384 + stw); \
  gld_lds16(pA[h][1] + (size_t)(kt) * 128, lds + (buf) * 65536 + (h) * 16384 + 8192 + stw); } while (0)
#define STB1(buf, h, kt) do { \
  gld_lds16(pB00 + (size_t)(h) * 128 * 2048 + (size_t)(kt) * 128, \
            lds + (buf) * 65536 + 32768 + (h) * 16384 + stw); \
  gld_lds16(pB00 + ((size_t)(h) * 128 + 64) * 2048 + (size_t)(kt) * 128, \
            lds + (buf) * 65536 + 32768 + (h) * 16384 + 8192 + stw); } while (0)

  FRAG_OFFSETS256();
  const int wmOff = wm * 16384;
  const int wnOff = 32768 + (wn >> 1) * 16384;

  f32x4 acc[8][4];
  #pragma unroll
  for (int a = 0; a < 8; ++a)
    #pragma unroll
    for (int b = 0; b < 4; ++b) acc[a][b] = (f32x4){0.f, 0.f, 0.f, 0.f};
  bf16x8 af[4][2], b0r[2][2], b1r[2][2];

  STA1(0, 0, 0); STA1(0, 1, 0); STB1(0, 0, 0); STB1(0, 1, 0);
  STB1(1, 0, 1); STB1(1, 1, 1);
  asm volatile("s_waitcnt vmcnt(4)" ::: "memory");
  __builtin_amdgcn_sched_barrier(0);
  __builtin_amdgcn_s_barrier();
  __builtin_amdgcn_sched_barrier(0);

  #pragma unroll 1
  for (int i = 0; i < NKT1 / 2; ++i) {
    const int k1 = 2 * i + 1, k2 = 2 * i + 2, k3 = 2 * i + 3;
    RDA(0, 0); RDB(0, 0, b0r); STA1(1, 0, k1); SYNC_PRE(); MMA(0, 0, b0r); SYNC_POST();
    RDB(0, 1, b1r);            STA1(1, 1, k1); SYNC_PRE(); MMA(0, 1, b1r); SYNC_POST();
    RDA(0, 1);                 STB1(0, 0, k2); SYNC_PRE(); MMA(1, 1, b1r); SYNC_POST();
                               STB1(0, 1, k2); SYNC_PRE(); MMA(1, 0, b0r); SYNC_POST_VM();
    RDA(1, 0); RDB(1, 0, b0r); STA1(0, 0, k2); SYNC_PRE(); MMA(0, 0, b0r); SYNC_POST();
    RDB(1, 1, b1r);            STA1(0, 1, k2); SYNC_PRE(); MMA(0, 1, b1r); SYNC_POST();
    RDA(1, 1);                 STB1(1, 0, k3); SYNC_PRE(); MMA(1, 1, b1r); SYNC_POST();
                               STB1(1, 1, k3); SYNC_PRE(); MMA(1, 0, b0r); SYNC_POST_VM();
  }

  asm volatile("s_waitcnt vmcnt(0)" ::: "memory");
  __builtin_amdgcn_sched_barrier(0);
  __syncthreads();
  // bias + relu -> LDS bf16 [256][512B] swizzled -> coalesced store
  #pragma unroll
  for (int na = 0; na < 4; ++na) {
    int c = wn * 64 + (na >> 1) * 32 + (na & 1) * 16 + (lane & 15);
    float bias = b1[(size_t)e * FD + n0 + c];
    #pragma unroll
    for (int ma = 0; ma < 8; ++ma) {
      #pragma unroll
      for (int j2 = 0; j2 < 4; ++j2) {
        int r = wm * 128 + (ma >> 2) * 64 + (ma & 3) * 16 + ((lane >> 4) << 2) + j2;
        float v = fmaxf(acc[ma][na][j2] + bias, 0.f);
        *(unsigned short*)(lds + r * 512 + ((c * 2) ^ ((r & 7) << 4))) = f2bf(v);
      }
    }
  }
  __syncthreads();
  #pragma unroll
  for (int s = 0; s < 16; ++s) {
    int flat = s * 512 + tid;
    int r = flat >> 5, ch = flat & 31;
    bf16x8 v = *(const bf16x8*)(lds + r * 512 + ((ch * 16) ^ ((r & 7) << 4)));
    *(bf16x8*)((char*)hbuf + (size_t)(row0 + r) * 8192 + (size_t)n0 * 2 + ch * 16) = v;
  }
#undef STA1
#undef STB1
}

// ---------------- GEMM2: fulls -> out2; tail quarter-K jobs -> psplit ----------------
__global__ __launch_bounds__(512, 2) void k_gemm2(const unsigned short* __restrict__ hbuf,
                                                  const unsigned short* __restrict__ w2t,
                                                  const float* __restrict__ b2,
                                                  const int* __restrict__ rowmap,
                                                  const float* __restrict__ roww,
                                                  const int* __restrict__ offs,
                                                  float* __restrict__ out2,
                                                  float* __restrict__ psplit) {
  __shared__ char lds[131072];
  const int id = blockIdx.x;
  int bx, by, kt0, niter, jj = -1;
  if (id < 256) {
    const int sid = (id & 7) * 32 + (id >> 3);   // bijective over 256
    bx = sid & 3; by = sid >> 2;                 // by < 64: always valid
    kt0 = 0; niter = 32;
  } else {
    const int jid = id - 256;
    const int q = (jid & 7) * 16 + (jid >> 3);   // bijective over 128
    const int t = 256 + (q >> 2);
    const int nT2 = (offs[8] >> 8) * 4;
    if (t >= nT2) return;
    bx = t & 3; by = t >> 2;
    kt0 = (q & 3) * 16; niter = 8;
    jj = q;
  }
  const int row0 = by * 256;
  int e = 0;
  #pragma unroll
  for (int i = 1; i < 8; ++i) if (row0 >= offs[i]) e = i;
  const int n0 = bx * 256;
  const int tid = threadIdx.x;
  const int lane = tid & 63;
  const int wid = tid >> 6;
  const int wm = wid >> 2, wn = wid & 3;

  const int rl = tid >> 3;
  const int cbs = ((tid & 7) << 4) ^ ((rl & 7) << 4);
  const char* pA00 = (const char*)hbuf + (size_t)(row0 + rl) * 8192 + cbs;
  const char* pB00 = (const char*)w2t + (size_t)e * ((size_t)HD * FD * 2) +
                     (size_t)(n0 + rl) * 8192 + cbs;
  const int stw = wid * 1024;

#define STA2(buf, h, kt) do { \
  gld_lds16(pA00 + (size_t)(h) * 128 * 8192 + (size_t)(kt) * 128, \
            lds + (buf) * 65536 + (h) * 16384 + stw); \
  gld_lds16(pA00 + ((size_t)(h) * 128 + 64) * 8192 + (size_t)(kt) * 128, \
            lds + (buf) * 65536 + (h) * 16384 + 8192 + stw); } while (0)
#define STB2(buf, h, kt) do { \
  gld_lds16(pB00 + (size_t)(h) * 128 * 8192 + (size_t)(kt) * 128, \
            lds + (buf) * 65536 + 32768 + (h) * 16384 + stw); \
  gld_lds16(pB00 + ((size_t)(h) * 128 + 64) * 8192 + (size_t)(kt) * 128, \
            lds + (buf) * 65536 + 32768 + (h) * 16384 + 8192 + stw); } while (0)

  FRAG_OFFSETS256();
  const int wmOff = wm * 16384;
  const int wnOff = 32768 + (wn >> 1) * 16384;

  f32x4 acc[8][4];
  #pragma unroll
  for (int a = 0; a < 8; ++a)
    #pragma unroll
    for (int b = 0; b < 4; ++b) acc[a][b] = (f32x4){0.f, 0.f, 0.f, 0.f};
  bf16x8 af[4][2], b0r[2][2], b1r[2][2];

  STA2(0, 0, kt0); STA2(0, 1, kt0); STB2(0, 0, kt0); STB2(0, 1, kt0);
  STB2(1, 0, kt0 + 1); STB2(1, 1, kt0 + 1);
  asm volatile("s_waitcnt vmcnt(4)" ::: "memory");
  __builtin_amdgcn_sched_barrier(0);
  __builtin_amdgcn_s_barrier();
  __builtin_amdgcn_sched_barrier(0);

  #pragma unroll 1
  for (int i = 0; i < niter; ++i) {
    const int k1 = kt0 + 2 * i + 1, k2 = kt0 + 2 * i + 2, k3 = kt0 + 2 * i + 3;
    RDA(0, 0); RDB(0, 0, b0r); STA2(1, 0, k1); SYNC_PRE(); MMA(0, 0, b0r); SYNC_POST();
    RDB(0, 1, b1r);            STA2(1, 1, k1); SYNC_PRE(); MMA(0, 1, b1r); SYNC_POST();
    RDA(0, 1);                 STB2(0, 0, k2); SYNC_PRE(); MMA(1, 1, b1r); SYNC_POST();
                               STB2(0, 1, k2); SYNC_PRE(); MMA(1, 0, b0r); SYNC_POST_VM();
    RDA(1, 0); RDB(1, 0, b0r); STA2(0, 0, k2); SYNC_PRE(); MMA(0, 0, b0r); SYNC_POST();
    RDB(1, 1, b1r);            STA2(0, 1, k2); SYNC_PRE(); MMA(0, 1, b1r); SYNC_POST();
    RDA(1, 1);                 STB2(1, 0, k3); SYNC_PRE(); MMA(1, 1, b1r); SYNC_POST();
                               STB2(1, 1, k3); SYNC_PRE(); MMA(1, 0, b0r); SYNC_POST_VM();
  }

  asm volatile("s_waitcnt vmcnt(0)" ::: "memory");
  __builtin_amdgcn_sched_barrier(0);
  if (jj < 0) {
    // full tile: bias + weight scale -> out2 slot rows (padding -> trash row)
    #pragma unroll
    for (int ma = 0; ma < 8; ++ma) {
      #pragma unroll
      for (int j2 = 0; j2 < 4; ++j2) {
        int r = wm * 128 + (ma >> 2) * 64 + (ma & 3) * 16 + ((lane >> 4) << 2) + j2;
        int rm = rowmap[row0 + r];
        float wr = roww[row0 + r];
        float* orow = out2 + (size_t)rm * 1024 + n0;
        #pragma unroll
        for (int na = 0; na < 4; ++na) {
          int c = wn * 64 + (na >> 1) * 32 + (na & 1) * 16 + (lane & 15);
          orow[c] = (acc[ma][na][j2] + b2[(size_t)e * HD + n0 + c]) * wr;
        }
      }
    }
  } else {
    // quarter job: raw partial sums -> psplit[jj][256][256]
    float* ps = psplit + (size_t)jj * 65536;
    #pragma unroll
    for (int ma = 0; ma < 8; ++ma) {
      #pragma unroll
      for (int j2 = 0; j2 < 4; ++j2) {
        int r = wm * 128 + (ma >> 2) * 64 + (ma & 3) * 16 + ((lane >> 4) << 2) + j2;
        #pragma unroll
        for (int na = 0; na < 4; ++na) {
          int c = wn * 64 + (na >> 1) * 32 + (na & 1) * 16 + (lane & 15);
          ps[r * 256 + c] = acc[ma][na][j2];
        }
      }
    }
  }
#undef STA2
#undef STB2
}

// ---------------- fix2: combine quarter partials of tail tiles into out2 ----------------
__global__ __launch_bounds__(512) void k_fix2(const float* __restrict__ psplit,
                                              const int* __restrict__ offs,
                                              const float* __restrict__ b2,
                                              const int* __restrict__ rowmap,
                                              const float* __restrict__ roww,
                                              float* __restrict__ out2) {
  const int nT2 = (offs[8] >> 8) * 4;
  const int t = 256 + blockIdx.x;
  if (t >= nT2) return;
  const int by = t >> 2, bx = t & 3;
  const int row0 = by * 256, n0 = bx * 256;
  int e = 0;
  #pragma unroll
  for (int i = 1; i < 8; ++i) if (row0 >= offs[i]) e = i;
  const float* ps = psplit + (size_t)blockIdx.x * 4 * 65536;
  const int cg = (threadIdx.x & 63) * 4;
  const int r0t = threadIdx.x >> 6;
  float4 bb = *(const float4*)(b2 + (size_t)e * HD + n0 + cg);
  for (int rr = 0; rr < 32; ++rr) {
    int r = rr * 8 + r0t;
    int rm = rowmap[row0 + r];
    float wr = roww[row0 + r];
    float4 s0 = *(const float4*)(ps + 0 * 65536 + r * 256 + cg);
    float4 s1 = *(const float4*)(ps + 1 * 65536 + r * 256 + cg);
    float4 s2 = *(const float4*)(ps + 2 * 65536 + r * 256 + cg);
    float4 s3 = *(const float4*)(ps + 3 * 65536 + r * 256 + cg);
    float4 o;
    o.x = wr * (s0.x + s1.x + s2.x + s3.x + bb.x);
    o.y = wr * (s0.y + s1.y + s2.y + s3.y + bb.y);
    o.z = wr * (s0.z + s1.z + s2.z + s3.z + bb.z);
    o.w = wr * (s0.w + s1.w + s2.w + s3.w + bb.w);
    *(float4*)(out2 + (size_t)rm * 1024 + n0 + cg) = o;
  }
}

// ---------------- combine: out[t] = out2[2t] + out2[2t+1] ----------------
__global__ __launch_bounds__(256) void k_combine(const float* __restrict__ out2,
                                                 float* __restrict__ out) {
  const int t = blockIdx.x;
  const int i = threadIdx.x * 4;
  float4 a = *(const float4*)(out2 + (size_t)(2 * t) * 1024 + i);
  float4 b = *(const float4*)(out2 + (size_t)(2 * t + 1) * 1024 + i);
  float4 r;
  r.x = a.x + b.x; r.y = a.y + b.y; r.z = a.z + b.z; r.w = a.w + b.w;
  *(float4*)(out + (size_t)t * 1024 + i) = r;
}

extern "C" void kernel_launch(void* const* d_in, const int* in_sizes, int n_in,
                              void* d_out, int out_size, void* d_ws, size_t ws_size,
                              hipStream_t stream) {
  const float* x = (const float*)d_in[0];
  const float* gw = (const float*)d_in[1];
  const float* w1 = (const float*)d_in[2];
  const float* b1 = (const float*)d_in[3];
  const float* w2 = (const float*)d_in[4];
  const float* b2 = (const float*)d_in[5];
  float* out = (float*)d_out;

  char* ws = (char*)d_ws;
  size_t o = 0;
  unsigned short* w2t = (unsigned short*)(ws + o); o += (size_t)NE * HD * FD * 2;   // 64 MiB
  unsigned short* hbuf = (unsigned short*)(ws + o); o += (size_t)RALLOC * FD * 2;   // 144 MiB
  unsigned short* w1t = (unsigned short*)(ws + o);
  size_t w1t_off = o; o += (size_t)NE * FD * HD * 2;                                // 64 MiB
  unsigned short* xbf = (unsigned short*)(ws + o); o += (size_t)T_TOK * HD * 2;     // 16 MiB
  int* rowmap = (int*)(ws + o); o += (size_t)RALLOC * 4;
  float* roww = (float*)(ws + o); o += (size_t)RALLOC * 4;
  int* toke = (int*)(ws + o); o += (size_t)T_TOK * 2 * 4;
  float* tokw = (float*)(ws + o); o += (size_t)T_TOK * 2 * 4;
  double* part = (double*)(ws + o); o += (size_t)GATE_BLOCKS * 8 * 8;
  int* counts8 = (int*)(ws + o); o += (size_t)GATE_BLOCKS * 8 * 4;
  int* ctrl = (int*)(ws + o); o += 1024;
  int* offs = ctrl;            // 9 ints
  int* cursors = ctrl + 64;    // 8 cursors, stride 16 ints
  float* psplit = (float*)(ws + o); o += (size_t)128 * 65536 * 4;                   // 32 MiB
  // out2 aliases [w1t ∪ xbf] (both dead after gemm1): 64.004 MiB < 80 MiB
  float* out2 = (float*)(ws + w1t_off);

  k_prep<<<16384 + GATE_BLOCKS, 256, 0, stream>>>(w1, w2, w1t, w2t, x, gw, toke, tokw,
                                                  counts8, part, xbf);
  k_scan<<<1, 256, 0, stream>>>(counts8, offs, cursors, part, out + (size_t)T_TOK * HD,
                                rowmap, roww);
  k_scatter<<<T_TOK / 256, 256, 0, stream>>>(toke, tokw, cursors, rowmap, roww);
  k_gemm1<<<G1, 512, 0, stream>>>(xbf, w1t, b1, rowmap, offs, hbuf);
  k_gemm2<<<G2, 512, 0, stream>>>(hbuf, w2t, b2, rowmap, roww, offs, out2, psplit);
  k_fix2<<<32, 512, 0, stream>>>(psplit, offs, b2, rowmap, roww, out2);
  k_combine<<<T_TOK, 256, 0, stream>>>(out2, out);
}

// Round 14
// 469.474 us; speedup vs baseline: 1.0186x; 1.0144x over previous
//
#include <hip/hip_runtime.h>
#include <stdint.h>

#define T_TOK 8192
#define HD 1024
#define NE 8
#define FD 4096
#define RALLOC 18432
#define G1 1152
#define G2 384
#define NKT1 16
#define GATE_BLOCKS 1024

typedef __attribute__((ext_vector_type(8))) short bf16x8;
typedef __attribute__((ext_vector_type(4))) float f32x4;
typedef __attribute__((ext_vector_type(4))) short s16x4;

__device__ __forceinline__ unsigned short f2bf(float f) {
  unsigned u = __builtin_bit_cast(unsigned, f);
  u += 0x7fffu + ((u >> 16) & 1u);
  return (unsigned short)(u >> 16);
}

__device__ __forceinline__ void gld_lds16(const void* g, void* l) {
  __builtin_amdgcn_global_load_lds(
      (const __attribute__((address_space(1))) void*)g,
      (__attribute__((address_space(3))) void*)l, 16, 0, 0);
}

// ---------------- merged transpose + cvt: f32 [R][C] -> bf16 [C][R], both weights ----------------
__global__ __launch_bounds__(256) void k_transpose2(const float* __restrict__ w1,
                                                    const float* __restrict__ w2,
                                                    unsigned short* __restrict__ w1t,
                                                    unsigned short* __restrict__ w2t) {
  __shared__ unsigned short tile[64 * 80];
  const int i = blockIdx.x;
  const float* src;
  unsigned short* dst;
  int R, C, r0, c0;
  if (i < 8192) {
    const int e = i >> 10, rem = i & 1023;
    R = HD; C = FD; r0 = (rem >> 6) << 6; c0 = (rem & 63) << 6;
    src = w1 + (size_t)e * R * C; dst = w1t + (size_t)e * R * C;
  } else {
    const int e = (i - 8192) >> 10, rem = (i - 8192) & 1023;
    R = FD; C = HD; r0 = (rem >> 4) << 6; c0 = (rem & 15) << 6;
    src = w2 + (size_t)e * R * C; dst = w2t + (size_t)e * R * C;
  }
  const int tid = threadIdx.x;
  {
    const int r = tid >> 2, cg = (tid & 3) * 16;
    #pragma unroll
    for (int m = 0; m < 4; ++m) {
      float4 v = *(const float4*)(src + (size_t)(r0 + r) * C + c0 + cg + 4 * m);
      s16x4 pv;
      pv[0] = (short)f2bf(v.x); pv[1] = (short)f2bf(v.y);
      pv[2] = (short)f2bf(v.z); pv[3] = (short)f2bf(v.w);
      *(s16x4*)&tile[r * 80 + cg + 4 * m] = pv;
    }
  }
  __syncthreads();
  {
    const int c = tid >> 2, rg = (tid & 3) * 16;
    bf16x8 v0, v1;
    #pragma unroll
    for (int j = 0; j < 8; ++j) v0[j] = (short)tile[(rg + j) * 80 + c];
    #pragma unroll
    for (int j = 0; j < 8; ++j) v1[j] = (short)tile[(rg + 8 + j) * 80 + c];
    unsigned short* dp = dst + (size_t)(c0 + c) * R + r0 + rg;
    *(bf16x8*)dp = v0;
    *(bf16x8*)(dp + 8) = v1;
  }
}

// ---------------- gating: wave per token, gwT in LDS, f64 accum, LDS count histogram ----------------
__global__ __launch_bounds__(512) void k_gating(const float* __restrict__ x,
                                                const float* __restrict__ gw,
                                                int* __restrict__ toke,
                                                float* __restrict__ tokw,
                                                int* __restrict__ counts8,
                                                double* __restrict__ part,
                                                unsigned short* __restrict__ xbf) {
  __shared__ float gwT[8 * 1024];
  __shared__ double sp[8][8];
  __shared__ int scnt[8];
  const int tid = threadIdx.x;
  const int lane = tid & 63;
  const int w = tid >> 6;
  if (tid < 8) scnt[tid] = 0;
  #pragma unroll
  for (int rep = 0; rep < 16; ++rep) {
    int idx = rep * 512 + tid;
    gwT[(idx & 7) * 1024 + (idx >> 3)] = gw[idx];
  }
  __syncthreads();

  const int t = blockIdx.x * 8 + w;
  double acc[8];
  #pragma unroll
  for (int e = 0; e < 8; ++e) acc[e] = 0.0;
  const float* xr = x + (size_t)t * HD;
  unsigned short* xbr = xbf + (size_t)t * HD;
  #pragma unroll
  for (int j = 0; j < 4; ++j) {
    const int hh = j * 256 + lane * 4;
    float4 xv = *(const float4*)(xr + hh);
    s16x4 pv;
    pv[0] = (short)f2bf(xv.x); pv[1] = (short)f2bf(xv.y);
    pv[2] = (short)f2bf(xv.z); pv[3] = (short)f2bf(xv.w);
    *(s16x4*)(xbr + hh) = pv;
    #pragma unroll
    for (int e = 0; e < 8; ++e) {
      float4 gv = *(const float4*)(gwT + e * 1024 + hh);
      acc[e] += (double)xv.x * (double)gv.x;
      acc[e] += (double)xv.y * (double)gv.y;
      acc[e] += (double)xv.z * (double)gv.z;
      acc[e] += (double)xv.w * (double)gv.w;
    }
  }
  for (int off = 32; off > 0; off >>= 1) {
    #pragma unroll
    for (int e = 0; e < 8; ++e) acc[e] += __shfl_xor(acc[e], off, 64);
  }
  double m = acc[0];
  #pragma unroll
  for (int e = 1; e < 8; ++e) m = fmax(m, acc[e]);
  double p[8], ssum = 0.0;
  #pragma unroll
  for (int e = 0; e < 8; ++e) { p[e] = exp(acc[e] - m); ssum += p[e]; }
  double inv = 1.0 / ssum;
  #pragma unroll
  for (int e = 0; e < 8; ++e) p[e] *= inv;
  int e0 = 0;
  #pragma unroll
  for (int e = 1; e < 8; ++e) if (p[e] > p[e0]) e0 = e;
  int e1 = (e0 == 0) ? 1 : 0;
  #pragma unroll
  for (int e = 0; e < 8; ++e) if (e != e0 && p[e] > p[e1]) e1 = e;
  if (lane == 0) {
    double z = exp(p[e1] - p[e0]);   // <= 1
    double w0 = 1.0 / (1.0 + z);
    toke[2 * t] = e0; toke[2 * t + 1] = e1;
    tokw[2 * t] = (float)w0; tokw[2 * t + 1] = (float)(z / (1.0 + z));
    atomicAdd(&scnt[e0], 1);
    atomicAdd(&scnt[e1], 1);
    #pragma unroll
    for (int e = 0; e < 8; ++e) sp[w][e] = p[e];
  }
  __syncthreads();
  if (tid < 8) {
    double s = 0.0;
    #pragma unroll
    for (int q = 0; q < 8; ++q) s += sp[q][tid];
    part[(size_t)blockIdx.x * 8 + tid] = s;
    counts8[(size_t)blockIdx.x * 8 + tid] = scnt[tid];
  }
}

// ---------------- scan: offsets (256-padded), loss, padding fill ----------------
__global__ __launch_bounds__(256) void k_scan(const int* __restrict__ counts8,
                                              int* __restrict__ offs,
                                              int* __restrict__ cursors,
                                              const double* __restrict__ part,
                                              float* __restrict__ loss_out,
                                              int* __restrict__ rowmap,
                                              float* __restrict__ roww) {
  __shared__ double su[8];
  __shared__ int soffs[9];
  __shared__ int scnt[8];
  const int tid = threadIdx.x;
  const int e = tid >> 5, sub = tid & 31;
  double s = 0.0;
  int c = 0;
  for (int b = sub; b < GATE_BLOCKS; b += 32) {
    s += part[(size_t)b * 8 + e];
    c += counts8[(size_t)b * 8 + e];
  }
  for (int off = 16; off > 0; off >>= 1) {
    s += __shfl_xor(s, off, 64);
    c += __shfl_xor(c, off, 64);
  }
  if (sub == 0) { su[e] = s; scnt[e] = c; }
  __syncthreads();
  if (tid == 0) {
    int o = 0;
    for (int i = 0; i < 8; ++i) {
      soffs[i] = o; offs[i] = o; cursors[i * 16] = o;
      o += ((scnt[i] + 255) >> 8) << 8;
    }
    soffs[8] = o; offs[8] = o;
    double u[8], mx = -1e300;
    for (int i = 0; i < 8; ++i) { u[i] = su[i] / 8192.0; mx = fmax(mx, u[i]); }
    double se = 0.0;
    for (int i = 0; i < 8; ++i) se += exp(u[i] - mx);
    double lse = mx + log(se);
    double kl = 0.0;
    const double lu = log(0.125);
    for (int i = 0; i < 8; ++i) kl += 0.125 * (lu - (u[i] - lse));
    kl /= 8.0;
    loss_out[0] = (float)(0.01 * kl);
  }
  __syncthreads();
  for (int i = 0; i < 8; ++i) {
    int s0 = soffs[i] + scnt[i];
    int en = soffs[i + 1];
    for (int k = s0 + tid; k < en; k += 256) { rowmap[k] = 2 * T_TOK; roww[k] = 0.f; }
  }
}

// ---------------- scatter: rowmap entries encode 2*t+k; cursors line-padded ----------------
__global__ __launch_bounds__(256) void k_scatter(const int* __restrict__ toke,
                                                 const float* __restrict__ tokw,
                                                 int* __restrict__ cursors,
                                                 int* __restrict__ rowmap,
                                                 float* __restrict__ roww) {
  const int t = blockIdx.x * 256 + threadIdx.x;
  const int lane = threadIdx.x & 63;
  #pragma unroll
  for (int k = 0; k < 2; ++k) {
    int e = toke[2 * t + k];
    float wv = tokw[2 * t + k];
    for (int ex = 0; ex < 8; ++ex) {
      unsigned long long mask = __ballot(e == ex);
      if (e == ex) {
        int leader = __ffsll((unsigned long long)mask) - 1;
        int rank = __popcll(mask & ((1ull << lane) - 1ull));
        int base = 0;
        if (lane == leader) base = atomicAdd(&cursors[ex * 16], __popcll(mask));
        base = __shfl(base, leader, 64);
        rowmap[base + rank] = 2 * t + k;
        roww[base + rank] = wv;
      }
    }
  }
}

// ======== 256x256 8-phase GEMM machinery (R11-proven fine interleave) ========
#define RDA(buf, mh) do { _Pragma("unroll") for (int m_ = 0; m_ < 4; ++m_) { \
  af[m_][0] = *(const bf16x8*)(lds + (buf) * 65536 + wmOff + (mh) * 8192 + aoff[m_][0]); \
  af[m_][1] = *(const bf16x8*)(lds + (buf) * 65536 + wmOff + (mh) * 8192 + aoff[m_][1]); } } while (0)

#define RDB(buf, nh, B) do { _Pragma("unroll") for (int nf_ = 0; nf_ < 2; ++nf_) { \
  B[nf_][0] = *(const bf16x8*)(lds + (buf) * 65536 + wnOff + (nh) * 4096 + boff[nf_][0]); \
  B[nf_][1] = *(const bf16x8*)(lds + (buf) * 65536 + wnOff + (nh) * 4096 + boff[nf_][1]); } } while (0)

#define MMA(mh, nh, B) do { _Pragma("unroll") for (int m_ = 0; m_ < 4; ++m_) \
  _Pragma("unroll") for (int nf_ = 0; nf_ < 2; ++nf_) \
  _Pragma("unroll") for (int kh_ = 0; kh_ < 2; ++kh_) \
    acc[(mh) * 4 + m_][(nh) * 2 + nf_] = __builtin_amdgcn_mfma_f32_16x16x32_bf16( \
        af[m_][kh_], B[nf_][kh_], acc[(mh) * 4 + m_][(nh) * 2 + nf_], 0, 0, 0); } while (0)

#define SYNC_PRE() do { __builtin_amdgcn_sched_barrier(0); __builtin_amdgcn_s_barrier(); \
  asm volatile("s_waitcnt lgkmcnt(0)" ::: "memory"); __builtin_amdgcn_sched_barrier(0); \
  __builtin_amdgcn_s_setprio(1); } while (0)

#define SYNC_POST() do { __builtin_amdgcn_s_setprio(0); __builtin_amdgcn_sched_barrier(0); \
  __builtin_amdgcn_s_barrier(); __builtin_amdgcn_sched_barrier(0); } while (0)

#define SYNC_POST_VM() do { __builtin_amdgcn_s_setprio(0); __builtin_amdgcn_sched_barrier(0); \
  asm volatile("s_waitcnt vmcnt(4)" ::: "memory"); __builtin_amdgcn_sched_barrier(0); \
  __builtin_amdgcn_s_barrier(); __builtin_amdgcn_sched_barrier(0); } while (0)

#define FRAG_OFFSETS256() \
  int aoff[4][2], boff[2][2]; \
  { \
    const int kg = (lane >> 4) << 4; \
    _Pragma("unroll") \
    for (int m = 0; m < 4; ++m) { \
      int r = m * 16 + (lane & 15); \
      _Pragma("unroll") \
      for (int kh = 0; kh < 2; ++kh) \
        aoff[m][kh] = r * 128 + ((kh * 64 + kg) ^ ((r & 7) << 4)); \
    } \
    _Pragma("unroll") \
    for (int nf = 0; nf < 2; ++nf) { \
      int r = (wn & 1) * 64 + nf * 16 + (lane & 15); \
      _Pragma("unroll") \
      for (int kh = 0; kh < 2; ++kh) \
        boff[nf][kh] = r * 128 + ((kh * 64 + kg) ^ ((r & 7) << 4)); \
    } \
  }

// ---------------- GEMM1: h = relu(gather(x_bf) @ w1t^T + b1), bf16 out ----------------
// XCD map: flattened balanced contiguous job runs per XCD ((rt,nb) lexicographic).
__global__ __launch_bounds__(512, 2) void k_gemm1(const unsigned short* __restrict__ xbf,
                                                  const unsigned short* __restrict__ w1t,
                                                  const float* __restrict__ b1,
                                                  const int* __restrict__ rowmap,
                                                  const int* __restrict__ offs,
                                                  unsigned short* __restrict__ hbuf) {
  __shared__ char lds[131072];
  const int id = blockIdx.x;
  const int xcd = id & 7, l = id >> 3;      // l in 0..143
  const int ntr = offs[8] >> 8;             // valid row-tiles (<= 72)
  const int nj = ntr * 16;                  // valid jobs (<= 1152)
  const int q = nj >> 3, r8 = nj & 7;
  const int cnt = q + (xcd < r8 ? 1 : 0);
  if (l >= cnt) return;
  const int start = (xcd < r8) ? xcd * (q + 1) : r8 * (q + 1) + (xcd - r8) * q;
  const int g = start + l;
  const int rt = g >> 4, nb = g & 15;
  const int row0 = rt * 256;
  int e = 0;
  #pragma unroll
  for (int i = 1; i < 8; ++i) if (row0 >= offs[i]) e = i;
  const int n0 = nb * 256;
  const int tid = threadIdx.x;
  const int lane = tid & 63;
  const int wid = tid >> 6;
  const int wm = wid >> 2, wn = wid & 3;

  const int rl = tid >> 3;
  const int cbs = ((tid & 7) << 4) ^ ((rl & 7) << 4);
  const char* pA[2][2];
  #pragma unroll
  for (int h = 0; h < 2; ++h)
    #pragma unroll
    for (int l2 = 0; l2 < 2; ++l2) {
      int tok = rowmap[row0 + h * 128 + l2 * 64 + rl] >> 1;
      pA[h][l2] = (const char*)xbf + (size_t)tok * 2048 + cbs;
    }
  const char* pB00 = (const char*)w1t + (size_t)e * ((size_t)FD * HD * 2) +
                     (size_t)(n0 + rl) * 2048 + cbs;
  const int stw = wid * 1024;

#define STA1(buf, h, kt) do { \
  gld_lds16(pA[h][0] + (size_t)(kt) * 128, lds + (buf) * 65536 + (h) * 16384 + stw); \
  gld_lds16(pA[h][1] + (size_t)(kt) * 128, lds + (buf) * 65536 + (h) * 16384 + 8192 + stw); } while (0)
#define STB1(buf, h, kt) do { \
  gld_lds16(pB00 + (size_t)(h) * 128 * 2048 + (size_t)(kt) * 128, \
            lds + (buf) * 65536 + 32768 + (h) * 16384 + stw); \
  gld_lds16(pB00 + ((size_t)(h) * 128 + 64) * 2048 + (size_t)(kt) * 128, \
            lds + (buf) * 65536 + 32768 + (h) * 16384 + 8192 + stw); } while (0)

  FRAG_OFFSETS256();
  const int wmOff = wm * 16384;
  const int wnOff = 32768 + (wn >> 1) * 16384;

  f32x4 acc[8][4];
  #pragma unroll
  for (int a = 0; a < 8; ++a)
    #pragma unroll
    for (int b = 0; b < 4; ++b) acc[a][b] = (f32x4){0.f, 0.f, 0.f, 0.f};
  bf16x8 af[4][2], b0r[2][2], b1r[2][2];

  STA1(0, 0, 0); STA1(0, 1, 0); STB1(0, 0, 0); STB1(0, 1, 0);
  STB1(1, 0, 1); STB1(1, 1, 1);
  asm volatile("s_waitcnt vmcnt(4)" ::: "memory");
  __builtin_amdgcn_sched_barrier(0);
  __builtin_amdgcn_s_barrier();
  __builtin_amdgcn_sched_barrier(0);

  #pragma unroll 1
  for (int i = 0; i < NKT1 / 2; ++i) {
    const int k1 = 2 * i + 1, k2 = 2 * i + 2, k3 = 2 * i + 3;
    RDA(0, 0); RDB(0, 0, b0r); STA1(1, 0, k1); SYNC_PRE(); MMA(0, 0, b0r); SYNC_POST();
    RDB(0, 1, b1r);            STA1(1, 1, k1); SYNC_PRE(); MMA(0, 1, b1r); SYNC_POST();
    RDA(0, 1);                 STB1(0, 0, k2); SYNC_PRE(); MMA(1, 1, b1r); SYNC_POST();
                               STB1(0, 1, k2); SYNC_PRE(); MMA(1, 0, b0r); SYNC_POST_VM();
    RDA(1, 0); RDB(1, 0, b0r); STA1(0, 0, k2); SYNC_PRE(); MMA(0, 0, b0r); SYNC_POST();
    RDB(1, 1, b1r);            STA1(0, 1, k2); SYNC_PRE(); MMA(0, 1, b1r); SYNC_POST();
    RDA(1, 1);                 STB1(1, 0, k3); SYNC_PRE(); MMA(1, 1, b1r); SYNC_POST();
                               STB1(1, 1, k3); SYNC_PRE(); MMA(1, 0, b0r); SYNC_POST_VM();
  }

  asm volatile("s_waitcnt vmcnt(0)" ::: "memory");
  __builtin_amdgcn_sched_barrier(0);
  __syncthreads();
  // bias + relu -> LDS bf16 [256][512B] swizzled -> coalesced store
  #pragma unroll
  for (int na = 0; na < 4; ++na) {
    int c = wn * 64 + (na >> 1) * 32 + (na & 1) * 16 + (lane & 15);
    float bias = b1[(size_t)e * FD + n0 + c];
    #pragma unroll
    for (int ma = 0; ma < 8; ++ma) {
      #pragma unroll
      for (int j2 = 0; j2 < 4; ++j2) {
        int r = wm * 128 + (ma >> 2) * 64 + (ma & 3) * 16 + ((lane >> 4) << 2) + j2;
        float v = fmaxf(acc[ma][na][j2] + bias, 0.f);
        *(unsigned short*)(lds + r * 512 + ((c * 2) ^ ((r & 7) << 4))) = f2bf(v);
      }
    }
  }
  __syncthreads();
  #pragma unroll
  for (int s = 0; s < 16; ++s) {
    int flat = s * 512 + tid;
    int r = flat >> 5, ch = flat & 31;
    bf16x8 v = *(const bf16x8*)(lds + r * 512 + ((ch * 16) ^ ((r & 7) << 4)));
    *(bf16x8*)((char*)hbuf + (size_t)(row0 + r) * 8192 + (size_t)n0 * 2 + ch * 16) = v;
  }
#undef STA1
#undef STB1
}

// ---------------- GEMM2: fulls -> out2; tail quarter-K jobs -> psplit ----------------
__global__ __launch_bounds__(512, 2) void k_gemm2(const unsigned short* __restrict__ hbuf,
                                                  const unsigned short* __restrict__ w2t,
                                                  const float* __restrict__ b2,
                                                  const int* __restrict__ rowmap,
                                                  const float* __restrict__ roww,
                                                  const int* __restrict__ offs,
                                                  float* __restrict__ out2,
                                                  float* __restrict__ psplit) {
  __shared__ char lds[131072];
  const int id = blockIdx.x;
  int bx, by, kt0, niter, jj = -1;
  if (id < 256) {
    const int sid = (id & 7) * 32 + (id >> 3);   // bijective over 256
    bx = sid & 3; by = sid >> 2;                 // by < 64: always valid
    kt0 = 0; niter = 32;
  } else {
    const int jid = id - 256;
    const int q = (jid & 7) * 16 + (jid >> 3);   // bijective over 128
    const int t = 256 + (q >> 2);
    const int nT2 = (offs[8] >> 8) * 4;
    if (t >= nT2) return;
    bx = t & 3; by = t >> 2;
    kt0 = (q & 3) * 16; niter = 8;
    jj = q;
  }
  const int row0 = by * 256;
  int e = 0;
  #pragma unroll
  for (int i = 1; i < 8; ++i) if (row0 >= offs[i]) e = i;
  const int n0 = bx * 256;
  const int tid = threadIdx.x;
  const int lane = tid & 63;
  const int wid = tid >> 6;
  const int wm = wid >> 2, wn = wid & 3;

  const int rl = tid >> 3;
  const int cbs = ((tid & 7) << 4) ^ ((rl & 7) << 4);
  const char* pA00 = (const char*)hbuf + (size_t)(row0 + rl) * 8192 + cbs;
  const char* pB00 = (const char*)w2t + (size_t)e * ((size_t)HD * FD * 2) +
                     (size_t)(n0 + rl) * 8192 + cbs;
  const int stw = wid * 1024;

#define STA2(buf, h, kt) do { \
  gld_lds16(pA00 + (size_t)(h) * 128 * 8192 + (size_t)(kt) * 128, \
            lds + (buf) * 65536 + (h) * 16384 + stw); \
  gld_lds16(pA00 + ((size_t)(h) * 128 + 64) * 8192 + (size_t)(kt) * 128, \
            lds + (buf) * 65536 + (h) * 16384 + 8192 + stw); } while (0)
#define STB2(buf, h, kt) do { \
  gld_lds16(pB00 + (size_t)(h) * 128 * 8192 + (size_t)(kt) * 128, \
            lds + (buf) * 65536 + 32768 + (h) * 16384 + stw); \
  gld_lds16(pB00 + ((size_t)(h) * 128 + 64) * 8192 + (size_t)(kt) * 128, \
            lds + (buf) * 65536 + 32768 + (h) * 16384 + 8192 + stw); } while (0)

  FRAG_OFFSETS256();
  const int wmOff = wm * 16384;
  const int wnOff = 32768 + (wn >> 1) * 16384;

  f32x4 acc[8][4];
  #pragma unroll
  for (int a = 0; a < 8; ++a)
    #pragma unroll
    for (int b = 0; b < 4; ++b) acc[a][b] = (f32x4){0.f, 0.f, 0.f, 0.f};
  bf16x8 af[4][2], b0r[2][2], b1r[2][2];

  STA2(0, 0, kt0); STA2(0, 1, kt0); STB2(0, 0, kt0); STB2(0, 1, kt0);
  STB2(1, 0, kt0 + 1); STB2(1, 1, kt0 + 1);
  asm volatile("s_waitcnt vmcnt(4)" ::: "memory");
  __builtin_amdgcn_sched_barrier(0);
  __builtin_amdgcn_s_barrier();
  __builtin_amdgcn_sched_barrier(0);

  #pragma unroll 1
  for (int i = 0; i < niter; ++i) {
    const int k1 = kt0 + 2 * i + 1, k2 = kt0 + 2 * i + 2, k3 = kt0 + 2 * i + 3;
    RDA(0, 0); RDB(0, 0, b0r); STA2(1, 0, k1); SYNC_PRE(); MMA(0, 0, b0r); SYNC_POST();
    RDB(0, 1, b1r);            STA2(1, 1, k1); SYNC_PRE(); MMA(0, 1, b1r); SYNC_POST();
    RDA(0, 1);                 STB2(0, 0, k2); SYNC_PRE(); MMA(1, 1, b1r); SYNC_POST();
                               STB2(0, 1, k2); SYNC_PRE(); MMA(1, 0, b0r); SYNC_POST_VM();
    RDA(1, 0); RDB(1, 0, b0r); STA2(0, 0, k2); SYNC_PRE(); MMA(0, 0, b0r); SYNC_POST();
    RDB(1, 1, b1r);            STA2(0, 1, k2); SYNC_PRE(); MMA(0, 1, b1r); SYNC_POST();
    RDA(1, 1);                 STB2(1, 0, k3); SYNC_PRE(); MMA(1, 1, b1r); SYNC_POST();
                               STB2(1, 1, k3); SYNC_PRE(); MMA(1, 0, b0r); SYNC_POST_VM();
  }

  asm volatile("s_waitcnt vmcnt(0)" ::: "memory");
  __builtin_amdgcn_sched_barrier(0);
  if (jj < 0) {
    // full tile: bias + weight scale -> out2 slot rows (padding -> trash row)
    #pragma unroll
    for (int ma = 0; ma < 8; ++ma) {
      #pragma unroll
      for (int j2 = 0; j2 < 4; ++j2) {
        int r = wm * 128 + (ma >> 2) * 64 + (ma & 3) * 16 + ((lane >> 4) << 2) + j2;
        int rm = rowmap[row0 + r];
        float wr = roww[row0 + r];
        float* orow = out2 + (size_t)rm * 1024 + n0;
        #pragma unroll
        for (int na = 0; na < 4; ++na) {
          int c = wn * 64 + (na >> 1) * 32 + (na & 1) * 16 + (lane & 15);
          orow[c] = (acc[ma][na][j2] + b2[(size_t)e * HD + n0 + c]) * wr;
        }
      }
    }
  } else {
    // quarter job: raw partial sums -> psplit[jj][256][256]
    float* ps = psplit + (size_t)jj * 65536;
    #pragma unroll
    for (int ma = 0; ma < 8; ++ma) {
      #pragma unroll
      for (int j2 = 0; j2 < 4; ++j2) {
        int r = wm * 128 + (ma >> 2) * 64 + (ma & 3) * 16 + ((lane >> 4) << 2) + j2;
        #pragma unroll
        for (int na = 0; na < 4; ++na) {
          int c = wn * 64 + (na >> 1) * 32 + (na & 1) * 16 + (lane & 15);
          ps[r * 256 + c] = acc[ma][na][j2];
        }
      }
    }
  }
#undef STA2
#undef STB2
}

// ---------------- fix2: combine quarter partials of tail tiles into out2 ----------------
__global__ __launch_bounds__(512) void k_fix2(const float* __restrict__ psplit,
                                              const int* __restrict__ offs,
                                              const float* __restrict__ b2,
                                              const int* __restrict__ rowmap,
                                              const float* __restrict__ roww,
                                              float* __restrict__ out2) {
  const int nT2 = (offs[8] >> 8) * 4;
  const int t = 256 + blockIdx.x;
  if (t >= nT2) return;
  const int by = t >> 2, bx = t & 3;
  const int row0 = by * 256, n0 = bx * 256;
  int e = 0;
  #pragma unroll
  for (int i = 1; i < 8; ++i) if (row0 >= offs[i]) e = i;
  const float* ps = psplit + (size_t)blockIdx.x * 4 * 65536;
  const int cg = (threadIdx.x & 63) * 4;
  const int r0t = threadIdx.x >> 6;
  float4 bb = *(const float4*)(b2 + (size_t)e * HD + n0 + cg);
  for (int rr = 0; rr < 32; ++rr) {
    int r = rr * 8 + r0t;
    int rm = rowmap[row0 + r];
    float wr = roww[row0 + r];
    float4 s0 = *(const float4*)(ps + 0 * 65536 + r * 256 + cg);
    float4 s1 = *(const float4*)(ps + 1 * 65536 + r * 256 + cg);
    float4 s2 = *(const float4*)(ps + 2 * 65536 + r * 256 + cg);
    float4 s3 = *(const float4*)(ps + 3 * 65536 + r * 256 + cg);
    float4 o;
    o.x = wr * (s0.x + s1.x + s2.x + s3.x + bb.x);
    o.y = wr * (s0.y + s1.y + s2.y + s3.y + bb.y);
    o.z = wr * (s0.z + s1.z + s2.z + s3.z + bb.z);
    o.w = wr * (s0.w + s1.w + s2.w + s3.w + bb.w);
    *(float4*)(out2 + (size_t)rm * 1024 + n0 + cg) = o;
  }
}

// ---------------- combine: out[t] = out2[2t] + out2[2t+1] ----------------
__global__ __launch_bounds__(256) void k_combine(const float* __restrict__ out2,
                                                 float* __restrict__ out) {
  const int t = blockIdx.x;
  const int i = threadIdx.x * 4;
  float4 a = *(const float4*)(out2 + (size_t)(2 * t) * 1024 + i);
  float4 b = *(const float4*)(out2 + (size_t)(2 * t + 1) * 1024 + i);
  float4 r;
  r.x = a.x + b.x; r.y = a.y + b.y; r.z = a.z + b.z; r.w = a.w + b.w;
  *(float4*)(out + (size_t)t * 1024 + i) = r;
}

extern "C" void kernel_launch(void* const* d_in, const int* in_sizes, int n_in,
                              void* d_out, int out_size, void* d_ws, size_t ws_size,
                              hipStream_t stream) {
  const float* x = (const float*)d_in[0];
  const float* gw = (const float*)d_in[1];
  const float* w1 = (const float*)d_in[2];
  const float* b1 = (const float*)d_in[3];
  const float* w2 = (const float*)d_in[4];
  const float* b2 = (const float*)d_in[5];
  float* out = (float*)d_out;

  char* ws = (char*)d_ws;
  size_t o = 0;
  unsigned short* w2t = (unsigned short*)(ws + o); o += (size_t)NE * HD * FD * 2;   // 64 MiB
  unsigned short* hbuf = (unsigned short*)(ws + o); o += (size_t)RALLOC * FD * 2;   // 144 MiB
  unsigned short* w1t = (unsigned short*)(ws + o);
  size_t w1t_off = o; o += (size_t)NE * FD * HD * 2;                                // 64 MiB
  unsigned short* xbf = (unsigned short*)(ws + o); o += (size_t)T_TOK * HD * 2;     // 16 MiB
  int* rowmap = (int*)(ws + o); o += (size_t)RALLOC * 4;
  float* roww = (float*)(ws + o); o += (size_t)RALLOC * 4;
  int* toke = (int*)(ws + o); o += (size_t)T_TOK * 2 * 4;
  float* tokw = (float*)(ws + o); o += (size_t)T_TOK * 2 * 4;
  double* part = (double*)(ws + o); o += (size_t)GATE_BLOCKS * 8 * 8;
  int* counts8 = (int*)(ws + o); o += (size_t)GATE_BLOCKS * 8 * 4;
  int* ctrl = (int*)(ws + o); o += 1024;
  int* offs = ctrl;            // 9 ints
  int* cursors = ctrl + 64;    // 8 cursors, stride 16 ints
  float* psplit = (float*)(ws + o); o += (size_t)128 * 65536 * 4;                   // 32 MiB
  // out2 aliases [w1t ∪ xbf] (both dead after gemm1): 64.004 MiB < 80 MiB
  float* out2 = (float*)(ws + w1t_off);

  k_transpose2<<<16384, 256, 0, stream>>>(w1, w2, w1t, w2t);
  k_gating<<<GATE_BLOCKS, 512, 0, stream>>>(x, gw, toke, tokw, counts8, part, xbf);
  k_scan<<<1, 256, 0, stream>>>(counts8, offs, cursors, part, out + (size_t)T_TOK * HD,
                                rowmap, roww);
  k_scatter<<<T_TOK / 256, 256, 0, stream>>>(toke, tokw, cursors, rowmap, roww);
  k_gemm1<<<G1, 512, 0, stream>>>(xbf, w1t, b1, rowmap, offs, hbuf);
  k_gemm2<<<G2, 512, 0, stream>>>(hbuf, w2t, b2, rowmap, roww, offs, out2, psplit);
  k_fix2<<<32, 512, 0, stream>>>(psplit, offs, b2, rowmap, roww, out2);
  k_combine<<<T_TOK, 256, 0, stream>>>(out2, out);
}

// Round 15
// 456.292 us; speedup vs baseline: 1.0481x; 1.0289x over previous
//
#include <hip/hip_runtime.h>
#include <stdint.h>

#define T_TOK 8192
#define HD 1024
#define NE 8
#define FD 4096
#define RALLOC 18432
#define G1 1152
#define G2 384
#define NKT1 16
#define GATE_BLOCKS 1024

typedef __attribute__((ext_vector_type(8))) short bf16x8;
typedef __attribute__((ext_vector_type(4))) float f32x4;
typedef __attribute__((ext_vector_type(4))) short s16x4;

__device__ __forceinline__ unsigned short f2bf(float f) {
  unsigned u = __builtin_bit_cast(unsigned, f);
  u += 0x7fffu + ((u >> 16) & 1u);
  return (unsigned short)(u >> 16);
}

__device__ __forceinline__ void gld_lds16(const void* g, void* l) {
  __builtin_amdgcn_global_load_lds(
      (const __attribute__((address_space(1))) void*)g,
      (__attribute__((address_space(3))) void*)l, 16, 0, 0);
}

// ---------------- transpose + cvt w1 only: f32 [H][F] -> bf16 [F][H] ----------------
__global__ __launch_bounds__(256) void k_transpose1(const float* __restrict__ w1,
                                                    unsigned short* __restrict__ w1t) {
  __shared__ unsigned short tile[64 * 80];
  const int i = blockIdx.x;
  const int e = i >> 10, rem = i & 1023;
  const int R = HD, C = FD;
  const int r0 = (rem >> 6) << 6, c0 = (rem & 63) << 6;
  const float* src = w1 + (size_t)e * R * C;
  unsigned short* dst = w1t + (size_t)e * R * C;
  const int tid = threadIdx.x;
  {
    const int r = tid >> 2, cg = (tid & 3) * 16;
    #pragma unroll
    for (int m = 0; m < 4; ++m) {
      float4 v = *(const float4*)(src + (size_t)(r0 + r) * C + c0 + cg + 4 * m);
      s16x4 pv;
      pv[0] = (short)f2bf(v.x); pv[1] = (short)f2bf(v.y);
      pv[2] = (short)f2bf(v.z); pv[3] = (short)f2bf(v.w);
      *(s16x4*)&tile[r * 80 + cg + 4 * m] = pv;
    }
  }
  __syncthreads();
  {
    const int c = tid >> 2, rg = (tid & 3) * 16;
    bf16x8 v0, v1;
    #pragma unroll
    for (int j = 0; j < 8; ++j) v0[j] = (short)tile[(rg + j) * 80 + c];
    #pragma unroll
    for (int j = 0; j < 8; ++j) v1[j] = (short)tile[(rg + 8 + j) * 80 + c];
    unsigned short* dp = dst + (size_t)(c0 + c) * R + r0 + rg;
    *(bf16x8*)dp = v0;
    *(bf16x8*)(dp + 8) = v1;
  }
}

// ---------------- gating: wave per token, gwT in LDS, f64 accum, LDS count histogram ----------------
__global__ __launch_bounds__(512) void k_gating(const float* __restrict__ x,
                                                const float* __restrict__ gw,
                                                int* __restrict__ toke,
                                                float* __restrict__ tokw,
                                                int* __restrict__ counts8,
                                                double* __restrict__ part,
                                                unsigned short* __restrict__ xbf) {
  __shared__ float gwT[8 * 1024];
  __shared__ double sp[8][8];
  __shared__ int scnt[8];
  const int tid = threadIdx.x;
  const int lane = tid & 63;
  const int w = tid >> 6;
  if (tid < 8) scnt[tid] = 0;
  #pragma unroll
  for (int rep = 0; rep < 16; ++rep) {
    int idx = rep * 512 + tid;
    gwT[(idx & 7) * 1024 + (idx >> 3)] = gw[idx];
  }
  __syncthreads();

  const int t = blockIdx.x * 8 + w;
  double acc[8];
  #pragma unroll
  for (int e = 0; e < 8; ++e) acc[e] = 0.0;
  const float* xr = x + (size_t)t * HD;
  unsigned short* xbr = xbf + (size_t)t * HD;
  #pragma unroll
  for (int j = 0; j < 4; ++j) {
    const int hh = j * 256 + lane * 4;
    float4 xv = *(const float4*)(xr + hh);
    s16x4 pv;
    pv[0] = (short)f2bf(xv.x); pv[1] = (short)f2bf(xv.y);
    pv[2] = (short)f2bf(xv.z); pv[3] = (short)f2bf(xv.w);
    *(s16x4*)(xbr + hh) = pv;
    #pragma unroll
    for (int e = 0; e < 8; ++e) {
      float4 gv = *(const float4*)(gwT + e * 1024 + hh);
      acc[e] += (double)xv.x * (double)gv.x;
      acc[e] += (double)xv.y * (double)gv.y;
      acc[e] += (double)xv.z * (double)gv.z;
      acc[e] += (double)xv.w * (double)gv.w;
    }
  }
  for (int off = 32; off > 0; off >>= 1) {
    #pragma unroll
    for (int e = 0; e < 8; ++e) acc[e] += __shfl_xor(acc[e], off, 64);
  }
  double m = acc[0];
  #pragma unroll
  for (int e = 1; e < 8; ++e) m = fmax(m, acc[e]);
  double p[8], ssum = 0.0;
  #pragma unroll
  for (int e = 0; e < 8; ++e) { p[e] = exp(acc[e] - m); ssum += p[e]; }
  double inv = 1.0 / ssum;
  #pragma unroll
  for (int e = 0; e < 8; ++e) p[e] *= inv;
  int e0 = 0;
  #pragma unroll
  for (int e = 1; e < 8; ++e) if (p[e] > p[e0]) e0 = e;
  int e1 = (e0 == 0) ? 1 : 0;
  #pragma unroll
  for (int e = 0; e < 8; ++e) if (e != e0 && p[e] > p[e1]) e1 = e;
  if (lane == 0) {
    double z = exp(p[e1] - p[e0]);   // <= 1
    double w0 = 1.0 / (1.0 + z);
    toke[2 * t] = e0; toke[2 * t + 1] = e1;
    tokw[2 * t] = (float)w0; tokw[2 * t + 1] = (float)(z / (1.0 + z));
    atomicAdd(&scnt[e0], 1);
    atomicAdd(&scnt[e1], 1);
    #pragma unroll
    for (int e = 0; e < 8; ++e) sp[w][e] = p[e];
  }
  __syncthreads();
  if (tid < 8) {
    double s = 0.0;
    #pragma unroll
    for (int q = 0; q < 8; ++q) s += sp[q][tid];
    part[(size_t)blockIdx.x * 8 + tid] = s;
    counts8[(size_t)blockIdx.x * 8 + tid] = scnt[tid];
  }
}

// ---------------- scan: offsets (256-padded), loss, padding fill ----------------
__global__ __launch_bounds__(256) void k_scan(const int* __restrict__ counts8,
                                              int* __restrict__ offs,
                                              int* __restrict__ cursors,
                                              const double* __restrict__ part,
                                              float* __restrict__ loss_out,
                                              int* __restrict__ rowmap,
                                              float* __restrict__ roww) {
  __shared__ double su[8];
  __shared__ int soffs[9];
  __shared__ int scnt[8];
  const int tid = threadIdx.x;
  const int e = tid >> 5, sub = tid & 31;
  double s = 0.0;
  int c = 0;
  for (int b = sub; b < GATE_BLOCKS; b += 32) {
    s += part[(size_t)b * 8 + e];
    c += counts8[(size_t)b * 8 + e];
  }
  for (int off = 16; off > 0; off >>= 1) {
    s += __shfl_xor(s, off, 64);
    c += __shfl_xor(c, off, 64);
  }
  if (sub == 0) { su[e] = s; scnt[e] = c; }
  __syncthreads();
  if (tid == 0) {
    int o = 0;
    for (int i = 0; i < 8; ++i) {
      soffs[i] = o; offs[i] = o; cursors[i * 16] = o;
      o += ((scnt[i] + 255) >> 8) << 8;
    }
    soffs[8] = o; offs[8] = o;
    double u[8], mx = -1e300;
    for (int i = 0; i < 8; ++i) { u[i] = su[i] / 8192.0; mx = fmax(mx, u[i]); }
    double se = 0.0;
    for (int i = 0; i < 8; ++i) se += exp(u[i] - mx);
    double lse = mx + log(se);
    double kl = 0.0;
    const double lu = log(0.125);
    for (int i = 0; i < 8; ++i) kl += 0.125 * (lu - (u[i] - lse));
    kl /= 8.0;
    loss_out[0] = (float)(0.01 * kl);
  }
  __syncthreads();
  for (int i = 0; i < 8; ++i) {
    int s0 = soffs[i] + scnt[i];
    int en = soffs[i + 1];
    for (int k = s0 + tid; k < en; k += 256) { rowmap[k] = 2 * T_TOK; roww[k] = 0.f; }
  }
}

// ---------------- scatter: rowmap entries encode 2*t+k; cursors line-padded ----------------
__global__ __launch_bounds__(256) void k_scatter(const int* __restrict__ toke,
                                                 const float* __restrict__ tokw,
                                                 int* __restrict__ cursors,
                                                 int* __restrict__ rowmap,
                                                 float* __restrict__ roww) {
  const int t = blockIdx.x * 256 + threadIdx.x;
  const int lane = threadIdx.x & 63;
  #pragma unroll
  for (int k = 0; k < 2; ++k) {
    int e = toke[2 * t + k];
    float wv = tokw[2 * t + k];
    for (int ex = 0; ex < 8; ++ex) {
      unsigned long long mask = __ballot(e == ex);
      if (e == ex) {
        int leader = __ffsll((unsigned long long)mask) - 1;
        int rank = __popcll(mask & ((1ull << lane) - 1ull));
        int base = 0;
        if (lane == leader) base = atomicAdd(&cursors[ex * 16], __popcll(mask));
        base = __shfl(base, leader, 64);
        rowmap[base + rank] = 2 * t + k;
        roww[base + rank] = wv;
      }
    }
  }
}

// ======== 256x256 8-phase GEMM machinery (R11-proven fine interleave) ========
#define RDA(buf, mh) do { _Pragma("unroll") for (int m_ = 0; m_ < 4; ++m_) { \
  af[m_][0] = *(const bf16x8*)(lds + (buf) * 65536 + wmOff + (mh) * 8192 + aoff[m_][0]); \
  af[m_][1] = *(const bf16x8*)(lds + (buf) * 65536 + wmOff + (mh) * 8192 + aoff[m_][1]); } } while (0)

#define RDB(buf, nh, B) do { _Pragma("unroll") for (int nf_ = 0; nf_ < 2; ++nf_) { \
  B[nf_][0] = *(const bf16x8*)(lds + (buf) * 65536 + wnOff + (nh) * 4096 + boff[nf_][0]); \
  B[nf_][1] = *(const bf16x8*)(lds + (buf) * 65536 + wnOff + (nh) * 4096 + boff[nf_][1]); } } while (0)

#define MMA(mh, nh, B) do { _Pragma("unroll") for (int m_ = 0; m_ < 4; ++m_) \
  _Pragma("unroll") for (int nf_ = 0; nf_ < 2; ++nf_) \
  _Pragma("unroll") for (int kh_ = 0; kh_ < 2; ++kh_) \
    acc[(mh) * 4 + m_][(nh) * 2 + nf_] = __builtin_amdgcn_mfma_f32_16x16x32_bf16( \
        af[m_][kh_], B[nf_][kh_], acc[(mh) * 4 + m_][(nh) * 2 + nf_], 0, 0, 0); } while (0)

#define SYNC_PRE() do { __builtin_amdgcn_sched_barrier(0); __builtin_amdgcn_s_barrier(); \
  asm volatile("s_waitcnt lgkmcnt(0)" ::: "memory"); __builtin_amdgcn_sched_barrier(0); \
  __builtin_amdgcn_s_setprio(1); } while (0)

#define SYNC_POST() do { __builtin_amdgcn_s_setprio(0); __builtin_amdgcn_sched_barrier(0); \
  __builtin_amdgcn_s_barrier(); __builtin_amdgcn_sched_barrier(0); } while (0)

#define SYNC_POST_VM() do { __builtin_amdgcn_s_setprio(0); __builtin_amdgcn_sched_barrier(0); \
  asm volatile("s_waitcnt vmcnt(4)" ::: "memory"); __builtin_amdgcn_sched_barrier(0); \
  __builtin_amdgcn_s_barrier(); __builtin_amdgcn_sched_barrier(0); } while (0)

#define FRAG_OFFSETS256() \
  int aoff[4][2], boff[2][2]; \
  { \
    const int kg = (lane >> 4) << 4; \
    _Pragma("unroll") \
    for (int m = 0; m < 4; ++m) { \
      int r = m * 16 + (lane & 15); \
      _Pragma("unroll") \
      for (int kh = 0; kh < 2; ++kh) \
        aoff[m][kh] = r * 128 + ((kh * 64 + kg) ^ ((r & 7) << 4)); \
    } \
    _Pragma("unroll") \
    for (int nf = 0; nf < 2; ++nf) { \
      int r = (wn & 1) * 64 + nf * 16 + (lane & 15); \
      _Pragma("unroll") \
      for (int kh = 0; kh < 2; ++kh) \
        boff[nf][kh] = r * 128 + ((kh * 64 + kg) ^ ((r & 7) << 4)); \
    } \
  }

// ---------------- GEMM1 (+ fused w2 transpose in trailing blocks) ----------------
// ids < G1: gemm1 (flattened balanced XCD job map); ids >= G1: w2 transpose, 2 tiles/block.
__global__ __launch_bounds__(512, 2) void k_gemm1(const unsigned short* __restrict__ xbf,
                                                  const unsigned short* __restrict__ w1t,
                                                  const float* __restrict__ b1,
                                                  const int* __restrict__ rowmap,
                                                  const int* __restrict__ offs,
                                                  unsigned short* __restrict__ hbuf,
                                                  const float* __restrict__ w2,
                                                  unsigned short* __restrict__ w2t) {
  __shared__ char lds[131072];
  const int id = blockIdx.x;
  const int tid = threadIdx.x;
  if (id >= G1) {
    // ---- w2 transpose: f32 [F][H] -> bf16 [H][F], two 64x64 tiles per block ----
    const int half = tid >> 8;          // 0 or 1
    const int t2 = tid & 255;
    unsigned short* tile = (unsigned short*)(lds + half * 10240);
    const int tt = (id - G1) * 2 + half;
    const int e = tt >> 10, rem = tt & 1023;
    const int R = FD, C = HD;
    const int r0 = (rem >> 4) << 6, c0 = (rem & 15) << 6;
    const float* src = w2 + (size_t)e * R * C;
    unsigned short* dst = w2t + (size_t)e * R * C;
    {
      const int r = t2 >> 2, cg = (t2 & 3) * 16;
      #pragma unroll
      for (int m = 0; m < 4; ++m) {
        float4 v = *(const float4*)(src + (size_t)(r0 + r) * C + c0 + cg + 4 * m);
        s16x4 pv;
        pv[0] = (short)f2bf(v.x); pv[1] = (short)f2bf(v.y);
        pv[2] = (short)f2bf(v.z); pv[3] = (short)f2bf(v.w);
        *(s16x4*)&tile[r * 80 + cg + 4 * m] = pv;
      }
    }
    __syncthreads();
    {
      const int c = t2 >> 2, rg = (t2 & 3) * 16;
      bf16x8 v0, v1;
      #pragma unroll
      for (int j = 0; j < 8; ++j) v0[j] = (short)tile[(rg + j) * 80 + c];
      #pragma unroll
      for (int j = 0; j < 8; ++j) v1[j] = (short)tile[(rg + 8 + j) * 80 + c];
      unsigned short* dp = dst + (size_t)(c0 + c) * R + r0 + rg;
      *(bf16x8*)dp = v0;
      *(bf16x8*)(dp + 8) = v1;
    }
    return;
  }
  const int xcd = id & 7, l = id >> 3;      // l in 0..143
  const int ntr = offs[8] >> 8;             // valid row-tiles (<= 72)
  const int nj = ntr * 16;                  // valid jobs (<= 1152)
  const int q = nj >> 3, r8 = nj & 7;
  const int cnt = q + (xcd < r8 ? 1 : 0);
  if (l >= cnt) return;
  const int start = (xcd < r8) ? xcd * (q + 1) : r8 * (q + 1) + (xcd - r8) * q;
  const int g = start + l;
  const int rt = g >> 4, nb = g & 15;
  const int row0 = rt * 256;
  int e = 0;
  #pragma unroll
  for (int i = 1; i < 8; ++i) if (row0 >= offs[i]) e = i;
  const int n0 = nb * 256;
  const int lane = tid & 63;
  const int wid = tid >> 6;
  const int wm = wid >> 2, wn = wid & 3;

  const int rl = tid >> 3;
  const int cbs = ((tid & 7) << 4) ^ ((rl & 7) << 4);
  const char* pA[2][2];
  #pragma unroll
  for (int h = 0; h < 2; ++h)
    #pragma unroll
    for (int l2 = 0; l2 < 2; ++l2) {
      int tok = rowmap[row0 + h * 128 + l2 * 64 + rl] >> 1;
      pA[h][l2] = (const char*)xbf + (size_t)tok * 2048 + cbs;
    }
  const char* pB00 = (const char*)w1t + (size_t)e * ((size_t)FD * HD * 2) +
                     (size_t)(n0 + rl) * 2048 + cbs;
  const int stw = wid * 1024;

#define STA1(buf, h, kt) do { \
  gld_lds16(pA[h][0] + (size_t)(kt) * 128, lds + (buf) * 65536 + (h) * 16384 + stw); \
  gld_lds16(pA[h][1] + (size_t)(kt) * 128, lds + (buf) * 65536 + (h) * 16384 + 8192 + stw); } while (0)
#define STB1(buf, h, kt) do { \
  gld_lds16(pB00 + (size_t)(h) * 128 * 2048 + (size_t)(kt) * 128, \
            lds + (buf) * 65536 + 32768 + (h) * 16384 + stw); \
  gld_lds16(pB00 + ((size_t)(h) * 128 + 64) * 2048 + (size_t)(kt) * 128, \
            lds + (buf) * 65536 + 32768 + (h) * 16384 + 8192 + stw); } while (0)

  FRAG_OFFSETS256();
  const int wmOff = wm * 16384;
  const int wnOff = 32768 + (wn >> 1) * 16384;

  f32x4 acc[8][4];
  #pragma unroll
  for (int a = 0; a < 8; ++a)
    #pragma unroll
    for (int b = 0; b < 4; ++b) acc[a][b] = (f32x4){0.f, 0.f, 0.f, 0.f};
  bf16x8 af[4][2], b0r[2][2], b1r[2][2];

  STA1(0, 0, 0); STA1(0, 1, 0); STB1(0, 0, 0); STB1(0, 1, 0);
  STB1(1, 0, 1); STB1(1, 1, 1);
  asm volatile("s_waitcnt vmcnt(4)" ::: "memory");
  __builtin_amdgcn_sched_barrier(0);
  __builtin_amdgcn_s_barrier();
  __builtin_amdgcn_sched_barrier(0);

  #pragma unroll 1
  for (int i = 0; i < NKT1 / 2; ++i) {
    const int k1 = 2 * i + 1, k2 = 2 * i + 2, k3 = 2 * i + 3;
    RDA(0, 0); RDB(0, 0, b0r); STA1(1, 0, k1); SYNC_PRE(); MMA(0, 0, b0r); SYNC_POST();
    RDB(0, 1, b1r);            STA1(1, 1, k1); SYNC_PRE(); MMA(0, 1, b1r); SYNC_POST();
    RDA(0, 1);                 STB1(0, 0, k2); SYNC_PRE(); MMA(1, 1, b1r); SYNC_POST();
                               STB1(0, 1, k2); SYNC_PRE(); MMA(1, 0, b0r); SYNC_POST_VM();
    RDA(1, 0); RDB(1, 0, b0r); STA1(0, 0, k2); SYNC_PRE(); MMA(0, 0, b0r); SYNC_POST();
    RDB(1, 1, b1r);            STA1(0, 1, k2); SYNC_PRE(); MMA(0, 1, b1r); SYNC_POST();
    RDA(1, 1);                 STB1(1, 0, k3); SYNC_PRE(); MMA(1, 1, b1r); SYNC_POST();
                               STB1(1, 1, k3); SYNC_PRE(); MMA(1, 0, b0r); SYNC_POST_VM();
  }

  asm volatile("s_waitcnt vmcnt(0)" ::: "memory");
  __builtin_amdgcn_sched_barrier(0);
  __syncthreads();
  // bias + relu -> LDS bf16 [256][512B] swizzled -> coalesced store
  #pragma unroll
  for (int na = 0; na < 4; ++na) {
    int c = wn * 64 + (na >> 1) * 32 + (na & 1) * 16 + (lane & 15);
    float bias = b1[(size_t)e * FD + n0 + c];
    #pragma unroll
    for (int ma = 0; ma < 8; ++ma) {
      #pragma unroll
      for (int j2 = 0; j2 < 4; ++j2) {
        int r = wm * 128 + (ma >> 2) * 64 + (ma & 3) * 16 + ((lane >> 4) << 2) + j2;
        float v = fmaxf(acc[ma][na][j2] + bias, 0.f);
        *(unsigned short*)(lds + r * 512 + ((c * 2) ^ ((r & 7) << 4))) = f2bf(v);
      }
    }
  }
  __syncthreads();
  #pragma unroll
  for (int s = 0; s < 16; ++s) {
    int flat = s * 512 + tid;
    int r = flat >> 5, ch = flat & 31;
    bf16x8 v = *(const bf16x8*)(lds + r * 512 + ((ch * 16) ^ ((r & 7) << 4)));
    *(bf16x8*)((char*)hbuf + (size_t)(row0 + r) * 8192 + (size_t)n0 * 2 + ch * 16) = v;
  }
#undef STA1
#undef STB1
}

// ---------------- GEMM2: fulls -> out2; tail quarter-K jobs -> psplit ----------------
__global__ __launch_bounds__(512, 2) void k_gemm2(const unsigned short* __restrict__ hbuf,
                                                  const unsigned short* __restrict__ w2t,
                                                  const float* __restrict__ b2,
                                                  const int* __restrict__ rowmap,
                                                  const float* __restrict__ roww,
                                                  const int* __restrict__ offs,
                                                  float* __restrict__ out2,
                                                  float* __restrict__ psplit) {
  __shared__ char lds[131072];
  const int id = blockIdx.x;
  int bx, by, kt0, niter, jj = -1;
  if (id < 256) {
    const int sid = (id & 7) * 32 + (id >> 3);   // bijective over 256
    bx = sid & 3; by = sid >> 2;                 // by < 64: always valid
    kt0 = 0; niter = 32;
  } else {
    const int jid = id - 256;
    const int q = (jid & 7) * 16 + (jid >> 3);   // bijective over 128
    const int t = 256 + (q >> 2);
    const int nT2 = (offs[8] >> 8) * 4;
    if (t >= nT2) return;
    bx = t & 3; by = t >> 2;
    kt0 = (q & 3) * 16; niter = 8;
    jj = q;
  }
  const int row0 = by * 256;
  int e = 0;
  #pragma unroll
  for (int i = 1; i < 8; ++i) if (row0 >= offs[i]) e = i;
  const int n0 = bx * 256;
  const int tid = threadIdx.x;
  const int lane = tid & 63;
  const int wid = tid >> 6;
  const int wm = wid >> 2, wn = wid & 3;

  const int rl = tid >> 3;
  const int cbs = ((tid & 7) << 4) ^ ((rl & 7) << 4);
  const char* pA00 = (const char*)hbuf + (size_t)(row0 + rl) * 8192 + cbs;
  const char* pB00 = (const char*)w2t + (size_t)e * ((size_t)HD * FD * 2) +
                     (size_t)(n0 + rl) * 8192 + cbs;
  const int stw = wid * 1024;

#define STA2(buf, h, kt) do { \
  gld_lds16(pA00 + (size_t)(h) * 128 * 8192 + (size_t)(kt) * 128, \
            lds + (buf) * 65536 + (h) * 16384 + stw); \
  gld_lds16(pA00 + ((size_t)(h) * 128 + 64) * 8192 + (size_t)(kt) * 128, \
            lds + (buf) * 65536 + (h) * 16384 + 8192 + stw); } while (0)
#define STB2(buf, h, kt) do { \
  gld_lds16(pB00 + (size_t)(h) * 128 * 8192 + (size_t)(kt) * 128, \
            lds + (buf) * 65536 + 32768 + (h) * 16384 + stw); \
  gld_lds16(pB00 + ((size_t)(h) * 128 + 64) * 8192 + (size_t)(kt) * 128, \
            lds + (buf) * 65536 + 32768 + (h) * 16384 + 8192 + stw); } while (0)

  FRAG_OFFSETS256();
  const int wmOff = wm * 16384;
  const int wnOff = 32768 + (wn >> 1) * 16384;

  f32x4 acc[8][4];
  #pragma unroll
  for (int a = 0; a < 8; ++a)
    #pragma unroll
    for (int b = 0; b < 4; ++b) acc[a][b] = (f32x4){0.f, 0.f, 0.f, 0.f};
  bf16x8 af[4][2], b0r[2][2], b1r[2][2];

  STA2(0, 0, kt0); STA2(0, 1, kt0); STB2(0, 0, kt0); STB2(0, 1, kt0);
  STB2(1, 0, kt0 + 1); STB2(1, 1, kt0 + 1);
  asm volatile("s_waitcnt vmcnt(4)" ::: "memory");
  __builtin_amdgcn_sched_barrier(0);
  __builtin_amdgcn_s_barrier();
  __builtin_amdgcn_sched_barrier(0);

  #pragma unroll 1
  for (int i = 0; i < niter; ++i) {
    const int k1 = kt0 + 2 * i + 1, k2 = kt0 + 2 * i + 2, k3 = kt0 + 2 * i + 3;
    RDA(0, 0); RDB(0, 0, b0r); STA2(1, 0, k1); SYNC_PRE(); MMA(0, 0, b0r); SYNC_POST();
    RDB(0, 1, b1r);            STA2(1, 1, k1); SYNC_PRE(); MMA(0, 1, b1r); SYNC_POST();
    RDA(0, 1);                 STB2(0, 0, k2); SYNC_PRE(); MMA(1, 1, b1r); SYNC_POST();
                               STB2(0, 1, k2); SYNC_PRE(); MMA(1, 0, b0r); SYNC_POST_VM();
    RDA(1, 0); RDB(1, 0, b0r); STA2(0, 0, k2); SYNC_PRE(); MMA(0, 0, b0r); SYNC_POST();
    RDB(1, 1, b1r);            STA2(0, 1, k2); SYNC_PRE(); MMA(0, 1, b1r); SYNC_POST();
    RDA(1, 1);                 STB2(1, 0, k3); SYNC_PRE(); MMA(1, 1, b1r); SYNC_POST();
                               STB2(1, 1, k3); SYNC_PRE(); MMA(1, 0, b0r); SYNC_POST_VM();
  }

  asm volatile("s_waitcnt vmcnt(0)" ::: "memory");
  __builtin_amdgcn_sched_barrier(0);
  if (jj < 0) {
    // full tile: bias + weight scale -> out2 slot rows (padding -> trash row)
    #pragma unroll
    for (int ma = 0; ma < 8; ++ma) {
      #pragma unroll
      for (int j2 = 0; j2 < 4; ++j2) {
        int r = wm * 128 + (ma >> 2) * 64 + (ma & 3) * 16 + ((lane >> 4) << 2) + j2;
        int rm = rowmap[row0 + r];
        float wr = roww[row0 + r];
        float* orow = out2 + (size_t)rm * 1024 + n0;
        #pragma unroll
        for (int na = 0; na < 4; ++na) {
          int c = wn * 64 + (na >> 1) * 32 + (na & 1) * 16 + (lane & 15);
          orow[c] = (acc[ma][na][j2] + b2[(size_t)e * HD + n0 + c]) * wr;
        }
      }
    }
  } else {
    // quarter job: raw partial sums -> psplit[jj][256][256]
    float* ps = psplit + (size_t)jj * 65536;
    #pragma unroll
    for (int ma = 0; ma < 8; ++ma) {
      #pragma unroll
      for (int j2 = 0; j2 < 4; ++j2) {
        int r = wm * 128 + (ma >> 2) * 64 + (ma & 3) * 16 + ((lane >> 4) << 2) + j2;
        #pragma unroll
        for (int na = 0; na < 4; ++na) {
          int c = wn * 64 + (na >> 1) * 32 + (na & 1) * 16 + (lane & 15);
          ps[r * 256 + c] = acc[ma][na][j2];
        }
      }
    }
  }
#undef STA2
#undef STB2
}

// ---------------- fix2: combine quarter partials of tail tiles into out2 ----------------
__global__ __launch_bounds__(512) void k_fix2(const float* __restrict__ psplit,
                                              const int* __restrict__ offs,
                                              const float* __restrict__ b2,
                                              const int* __restrict__ rowmap,
                                              const float* __restrict__ roww,
                                              float* __restrict__ out2) {
  const int nT2 = (offs[8] >> 8) * 4;
  const int t = 256 + blockIdx.x;
  if (t >= nT2) return;
  const int by = t >> 2, bx = t & 3;
  const int row0 = by * 256, n0 = bx * 256;
  int e = 0;
  #pragma unroll
  for (int i = 1; i < 8; ++i) if (row0 >= offs[i]) e = i;
  const float* ps = psplit + (size_t)blockIdx.x * 4 * 65536;
  const int cg = (threadIdx.x & 63) * 4;
  const int r0t = threadIdx.x >> 6;
  float4 bb = *(const float4*)(b2 + (size_t)e * HD + n0 + cg);
  for (int rr = 0; rr < 32; ++rr) {
    int r = rr * 8 + r0t;
    int rm = rowmap[row0 + r];
    float wr = roww[row0 + r];
    float4 s0 = *(const float4*)(ps + 0 * 65536 + r * 256 + cg);
    float4 s1 = *(const float4*)(ps + 1 * 65536 + r * 256 + cg);
    float4 s2 = *(const float4*)(ps + 2 * 65536 + r * 256 + cg);
    float4 s3 = *(const float4*)(ps + 3 * 65536 + r * 256 + cg);
    float4 o;
    o.x = wr * (s0.x + s1.x + s2.x + s3.x + bb.x);
    o.y = wr * (s0.y + s1.y + s2.y + s3.y + bb.y);
    o.z = wr * (s0.z + s1.z + s2.z + s3.z + bb.z);
    o.w = wr * (s0.w + s1.w + s2.w + s3.w + bb.w);
    *(float4*)(out2 + (size_t)rm * 1024 + n0 + cg) = o;
  }
}

// ---------------- combine: out[t] = out2[2t] + out2[2t+1] ----------------
__global__ __launch_bounds__(256) void k_combine(const float* __restrict__ out2,
                                                 float* __restrict__ out) {
  const int t = blockIdx.x;
  const int i = threadIdx.x * 4;
  float4 a = *(const float4*)(out2 + (size_t)(2 * t) * 1024 + i);
  float4 b = *(const float4*)(out2 + (size_t)(2 * t + 1) * 1024 + i);
  float4 r;
  r.x = a.x + b.x; r.y = a.y + b.y; r.z = a.z + b.z; r.w = a.w + b.w;
  *(float4*)(out + (size_t)t * 1024 + i) = r;
}

extern "C" void kernel_launch(void* const* d_in, const int* in_sizes, int n_in,
                              void* d_out, int out_size, void* d_ws, size_t ws_size,
                              hipStream_t stream) {
  const float* x = (const float*)d_in[0];
  const float* gw = (const float*)d_in[1];
  const float* w1 = (const float*)d_in[2];
  const float* b1 = (const float*)d_in[3];
  const float* w2 = (const float*)d_in[4];
  const float* b2 = (const float*)d_in[5];
  float* out = (float*)d_out;

  char* ws = (char*)d_ws;
  size_t o = 0;
  unsigned short* w2t = (unsigned short*)(ws + o); o += (size_t)NE * HD * FD * 2;   // 64 MiB
  unsigned short* hbuf = (unsigned short*)(ws + o); o += (size_t)RALLOC * FD * 2;   // 144 MiB
  unsigned short* w1t = (unsigned short*)(ws + o);
  size_t w1t_off = o; o += (size_t)NE * FD * HD * 2;                                // 64 MiB
  unsigned short* xbf = (unsigned short*)(ws + o); o += (size_t)T_TOK * HD * 2;     // 16 MiB
  int* rowmap = (int*)(ws + o); o += (size_t)RALLOC * 4;
  float* roww = (float*)(ws + o); o += (size_t)RALLOC * 4;
  int* toke = (int*)(ws + o); o += (size_t)T_TOK * 2 * 4;
  float* tokw = (float*)(ws + o); o += (size_t)T_TOK * 2 * 4;
  double* part = (double*)(ws + o); o += (size_t)GATE_BLOCKS * 8 * 8;
  int* counts8 = (int*)(ws + o); o += (size_t)GATE_BLOCKS * 8 * 4;
  int* ctrl = (int*)(ws + o); o += 1024;
  int* offs = ctrl;            // 9 ints
  int* cursors = ctrl + 64;    // 8 cursors, stride 16 ints
  float* psplit = (float*)(ws + o); o += (size_t)128 * 65536 * 4;                   // 32 MiB
  // out2 aliases [w1t ∪ xbf] (both dead after gemm1): 64.004 MiB < 80 MiB
  float* out2 = (float*)(ws + w1t_off);

  k_transpose1<<<8192, 256, 0, stream>>>(w1, w1t);
  k_gating<<<GATE_BLOCKS, 512, 0, stream>>>(x, gw, toke, tokw, counts8, part, xbf);
  k_scan<<<1, 256, 0, stream>>>(counts8, offs, cursors, part, out + (size_t)T_TOK * HD,
                                rowmap, roww);
  k_scatter<<<T_TOK / 256, 256, 0, stream>>>(toke, tokw, cursors, rowmap, roww);
  k_gemm1<<<G1 + 4096, 512, 0, stream>>>(xbf, w1t, b1, rowmap, offs, hbuf, w2, w2t);
  k_gemm2<<<G2, 512, 0, stream>>>(hbuf, w2t, b2, rowmap, roww, offs, out2, psplit);
  k_fix2<<<32, 512, 0, stream>>>(psplit, offs, b2, rowmap, roww, out2);
  k_combine<<<T_TOK, 256, 0, stream>>>(out2, out);
}

// Round 16
// 452.192 us; speedup vs baseline: 1.0576x; 1.0091x over previous
//
#include <hip/hip_runtime.h>
#include <stdint.h>

#define T_TOK 8192
#define HD 1024
#define NE 8
#define FD 4096
#define RALLOC 18432
#define G1 1152
#define G2 384
#define NKT1 16
#define GATE_BLOCKS 1024
#define TP1_BLOCKS 4096

typedef __attribute__((ext_vector_type(8))) short bf16x8;
typedef __attribute__((ext_vector_type(4))) float f32x4;
typedef __attribute__((ext_vector_type(4))) short s16x4;

__device__ __forceinline__ unsigned short f2bf(float f) {
  unsigned u = __builtin_bit_cast(unsigned, f);
  u += 0x7fffu + ((u >> 16) & 1u);
  return (unsigned short)(u >> 16);
}

__device__ __forceinline__ void gld_lds16(const void* g, void* l) {
  __builtin_amdgcn_global_load_lds(
      (const __attribute__((address_space(1))) void*)g,
      (__attribute__((address_space(3))) void*)l, 16, 0, 0);
}

// ---------------- prep1: fused w1 transpose (ids 0..4095, 2 tiles each) + gating (ids >= 4096) ----------------
__global__ __launch_bounds__(512) void k_prep1(const float* __restrict__ w1,
                                               unsigned short* __restrict__ w1t,
                                               const float* __restrict__ x,
                                               const float* __restrict__ gw,
                                               int* __restrict__ toke,
                                               float* __restrict__ tokw,
                                               int* __restrict__ counts8,
                                               double* __restrict__ part,
                                               unsigned short* __restrict__ xbf) {
  __shared__ char smem[33312];
  const int id = blockIdx.x;
  const int tid = threadIdx.x;
  if (id < TP1_BLOCKS) {
    // ---- w1 transpose: f32 [H][F] -> bf16 [F][H], two 64x64 tiles per block ----
    const int half = tid >> 8;
    const int t2 = tid & 255;
    unsigned short* tile = (unsigned short*)(smem + half * 10240);
    const int tt = id * 2 + half;
    const int e = tt >> 10, rem = tt & 1023;
    const int R = HD, C = FD;
    const int r0 = (rem >> 6) << 6, c0 = (rem & 63) << 6;
    const float* src = w1 + (size_t)e * R * C;
    unsigned short* dst = w1t + (size_t)e * R * C;
    {
      const int r = t2 >> 2, cg = (t2 & 3) * 16;
      #pragma unroll
      for (int m = 0; m < 4; ++m) {
        float4 v = *(const float4*)(src + (size_t)(r0 + r) * C + c0 + cg + 4 * m);
        s16x4 pv;
        pv[0] = (short)f2bf(v.x); pv[1] = (short)f2bf(v.y);
        pv[2] = (short)f2bf(v.z); pv[3] = (short)f2bf(v.w);
        *(s16x4*)&tile[r * 80 + cg + 4 * m] = pv;
      }
    }
    __syncthreads();
    {
      const int c = t2 >> 2, rg = (t2 & 3) * 16;
      bf16x8 v0, v1;
      #pragma unroll
      for (int j = 0; j < 8; ++j) v0[j] = (short)tile[(rg + j) * 80 + c];
      #pragma unroll
      for (int j = 0; j < 8; ++j) v1[j] = (short)tile[(rg + 8 + j) * 80 + c];
      unsigned short* dp = dst + (size_t)(c0 + c) * R + r0 + rg;
      *(bf16x8*)dp = v0;
      *(bf16x8*)(dp + 8) = v1;
    }
    return;
  }
  // ---- gating: wave per token (8/block), gwT in LDS, f64 accum, LDS histogram ----
  float* gwT = (float*)smem;                        // 32768 B
  double (*sp)[8] = (double(*)[8])(smem + 32768);   // 512 B
  int* scnt = (int*)(smem + 33280);                 // 32 B
  const int gb = id - TP1_BLOCKS;
  const int lane = tid & 63;
  const int w = tid >> 6;
  if (tid < 8) scnt[tid] = 0;
  #pragma unroll
  for (int rep = 0; rep < 16; ++rep) {
    int idx = rep * 512 + tid;
    gwT[(idx & 7) * 1024 + (idx >> 3)] = gw[idx];
  }
  __syncthreads();

  const int t = gb * 8 + w;
  double acc[8];
  #pragma unroll
  for (int e = 0; e < 8; ++e) acc[e] = 0.0;
  const float* xr = x + (size_t)t * HD;
  unsigned short* xbr = xbf + (size_t)t * HD;
  #pragma unroll
  for (int j = 0; j < 4; ++j) {
    const int hh = j * 256 + lane * 4;
    float4 xv = *(const float4*)(xr + hh);
    s16x4 pv;
    pv[0] = (short)f2bf(xv.x); pv[1] = (short)f2bf(xv.y);
    pv[2] = (short)f2bf(xv.z); pv[3] = (short)f2bf(xv.w);
    *(s16x4*)(xbr + hh) = pv;
    #pragma unroll
    for (int e = 0; e < 8; ++e) {
      float4 gv = *(const float4*)(gwT + e * 1024 + hh);
      acc[e] += (double)xv.x * (double)gv.x;
      acc[e] += (double)xv.y * (double)gv.y;
      acc[e] += (double)xv.z * (double)gv.z;
      acc[e] += (double)xv.w * (double)gv.w;
    }
  }
  for (int off = 32; off > 0; off >>= 1) {
    #pragma unroll
    for (int e = 0; e < 8; ++e) acc[e] += __shfl_xor(acc[e], off, 64);
  }
  double m = acc[0];
  #pragma unroll
  for (int e = 1; e < 8; ++e) m = fmax(m, acc[e]);
  double p[8], ssum = 0.0;
  #pragma unroll
  for (int e = 0; e < 8; ++e) { p[e] = exp(acc[e] - m); ssum += p[e]; }
  double inv = 1.0 / ssum;
  #pragma unroll
  for (int e = 0; e < 8; ++e) p[e] *= inv;
  int e0 = 0;
  #pragma unroll
  for (int e = 1; e < 8; ++e) if (p[e] > p[e0]) e0 = e;
  int e1 = (e0 == 0) ? 1 : 0;
  #pragma unroll
  for (int e = 0; e < 8; ++e) if (e != e0 && p[e] > p[e1]) e1 = e;
  if (lane == 0) {
    double z = exp(p[e1] - p[e0]);   // <= 1
    double w0 = 1.0 / (1.0 + z);
    toke[2 * t] = e0; toke[2 * t + 1] = e1;
    tokw[2 * t] = (float)w0; tokw[2 * t + 1] = (float)(z / (1.0 + z));
    atomicAdd(&scnt[e0], 1);
    atomicAdd(&scnt[e1], 1);
    #pragma unroll
    for (int e = 0; e < 8; ++e) sp[w][e] = p[e];
  }
  __syncthreads();
  if (tid < 8) {
    double s = 0.0;
    #pragma unroll
    for (int q = 0; q < 8; ++q) s += sp[q][tid];
    part[(size_t)gb * 8 + tid] = s;
    counts8[(size_t)gb * 8 + tid] = scnt[tid];
  }
}

// ---------------- scan: offsets (256-padded), loss, padding fill ----------------
__global__ __launch_bounds__(256) void k_scan(const int* __restrict__ counts8,
                                              int* __restrict__ offs,
                                              int* __restrict__ cursors,
                                              const double* __restrict__ part,
                                              float* __restrict__ loss_out,
                                              int* __restrict__ rowmap,
                                              float* __restrict__ roww) {
  __shared__ double su[8];
  __shared__ int soffs[9];
  __shared__ int scnt[8];
  const int tid = threadIdx.x;
  const int e = tid >> 5, sub = tid & 31;
  double s = 0.0;
  int c = 0;
  for (int b = sub; b < GATE_BLOCKS; b += 32) {
    s += part[(size_t)b * 8 + e];
    c += counts8[(size_t)b * 8 + e];
  }
  for (int off = 16; off > 0; off >>= 1) {
    s += __shfl_xor(s, off, 64);
    c += __shfl_xor(c, off, 64);
  }
  if (sub == 0) { su[e] = s; scnt[e] = c; }
  __syncthreads();
  if (tid == 0) {
    int o = 0;
    for (int i = 0; i < 8; ++i) {
      soffs[i] = o; offs[i] = o; cursors[i * 16] = o;
      o += ((scnt[i] + 255) >> 8) << 8;
    }
    soffs[8] = o; offs[8] = o;
    double u[8], mx = -1e300;
    for (int i = 0; i < 8; ++i) { u[i] = su[i] / 8192.0; mx = fmax(mx, u[i]); }
    double se = 0.0;
    for (int i = 0; i < 8; ++i) se += exp(u[i] - mx);
    double lse = mx + log(se);
    double kl = 0.0;
    const double lu = log(0.125);
    for (int i = 0; i < 8; ++i) kl += 0.125 * (lu - (u[i] - lse));
    kl /= 8.0;
    loss_out[0] = (float)(0.01 * kl);
  }
  __syncthreads();
  for (int i = 0; i < 8; ++i) {
    int s0 = soffs[i] + scnt[i];
    int en = soffs[i + 1];
    for (int k = s0 + tid; k < en; k += 256) { rowmap[k] = 2 * T_TOK; roww[k] = 0.f; }
  }
}

// ---------------- scatter: rowmap entries encode 2*t+k; cursors line-padded ----------------
__global__ __launch_bounds__(256) void k_scatter(const int* __restrict__ toke,
                                                 const float* __restrict__ tokw,
                                                 int* __restrict__ cursors,
                                                 int* __restrict__ rowmap,
                                                 float* __restrict__ roww) {
  const int t = blockIdx.x * 256 + threadIdx.x;
  const int lane = threadIdx.x & 63;
  #pragma unroll
  for (int k = 0; k < 2; ++k) {
    int e = toke[2 * t + k];
    float wv = tokw[2 * t + k];
    for (int ex = 0; ex < 8; ++ex) {
      unsigned long long mask = __ballot(e == ex);
      if (e == ex) {
        int leader = __ffsll((unsigned long long)mask) - 1;
        int rank = __popcll(mask & ((1ull << lane) - 1ull));
        int base = 0;
        if (lane == leader) base = atomicAdd(&cursors[ex * 16], __popcll(mask));
        base = __shfl(base, leader, 64);
        rowmap[base + rank] = 2 * t + k;
        roww[base + rank] = wv;
      }
    }
  }
}

// ======== 256x256 8-phase GEMM machinery (R11-proven fine interleave) ========
#define RDA(buf, mh) do { _Pragma("unroll") for (int m_ = 0; m_ < 4; ++m_) { \
  af[m_][0] = *(const bf16x8*)(lds + (buf) * 65536 + wmOff + (mh) * 8192 + aoff[m_][0]); \
  af[m_][1] = *(const bf16x8*)(lds + (buf) * 65536 + wmOff + (mh) * 8192 + aoff[m_][1]); } } while (0)

#define RDB(buf, nh, B) do { _Pragma("unroll") for (int nf_ = 0; nf_ < 2; ++nf_) { \
  B[nf_][0] = *(const bf16x8*)(lds + (buf) * 65536 + wnOff + (nh) * 4096 + boff[nf_][0]); \
  B[nf_][1] = *(const bf16x8*)(lds + (buf) * 65536 + wnOff + (nh) * 4096 + boff[nf_][1]); } } while (0)

#define MMA(mh, nh, B) do { _Pragma("unroll") for (int m_ = 0; m_ < 4; ++m_) \
  _Pragma("unroll") for (int nf_ = 0; nf_ < 2; ++nf_) \
  _Pragma("unroll") for (int kh_ = 0; kh_ < 2; ++kh_) \
    acc[(mh) * 4 + m_][(nh) * 2 + nf_] = __builtin_amdgcn_mfma_f32_16x16x32_bf16( \
        af[m_][kh_], B[nf_][kh_], acc[(mh) * 4 + m_][(nh) * 2 + nf_], 0, 0, 0); } while (0)

#define SYNC_PRE() do { __builtin_amdgcn_sched_barrier(0); __builtin_amdgcn_s_barrier(); \
  asm volatile("s_waitcnt lgkmcnt(0)" ::: "memory"); __builtin_amdgcn_sched_barrier(0); \
  __builtin_amdgcn_s_setprio(1); } while (0)

#define SYNC_POST() do { __builtin_amdgcn_s_setprio(0); __builtin_amdgcn_sched_barrier(0); \
  __builtin_amdgcn_s_barrier(); __builtin_amdgcn_sched_barrier(0); } while (0)

#define SYNC_POST_VM() do { __builtin_amdgcn_s_setprio(0); __builtin_amdgcn_sched_barrier(0); \
  asm volatile("s_waitcnt vmcnt(4)" ::: "memory"); __builtin_amdgcn_sched_barrier(0); \
  __builtin_amdgcn_s_barrier(); __builtin_amdgcn_sched_barrier(0); } while (0)

#define FRAG_OFFSETS256() \
  int aoff[4][2], boff[2][2]; \
  { \
    const int kg = (lane >> 4) << 4; \
    _Pragma("unroll") \
    for (int m = 0; m < 4; ++m) { \
      int r = m * 16 + (lane & 15); \
      _Pragma("unroll") \
      for (int kh = 0; kh < 2; ++kh) \
        aoff[m][kh] = r * 128 + ((kh * 64 + kg) ^ ((r & 7) << 4)); \
    } \
    _Pragma("unroll") \
    for (int nf = 0; nf < 2; ++nf) { \
      int r = (wn & 1) * 64 + nf * 16 + (lane & 15); \
      _Pragma("unroll") \
      for (int kh = 0; kh < 2; ++kh) \
        boff[nf][kh] = r * 128 + ((kh * 64 + kg) ^ ((r & 7) << 4)); \
    } \
  }

// ---------------- GEMM1 (+ fused w2 transpose in trailing blocks) ----------------
// ids < G1: gemm1 (flattened balanced XCD job map); ids >= G1: w2 transpose, 2 tiles/block.
__global__ __launch_bounds__(512, 2) void k_gemm1(const unsigned short* __restrict__ xbf,
                                                  const unsigned short* __restrict__ w1t,
                                                  const float* __restrict__ b1,
                                                  const int* __restrict__ rowmap,
                                                  const int* __restrict__ offs,
                                                  unsigned short* __restrict__ hbuf,
                                                  const float* __restrict__ w2,
                                                  unsigned short* __restrict__ w2t) {
  __shared__ char lds[131072];
  const int id = blockIdx.x;
  const int tid = threadIdx.x;
  if (id >= G1) {
    // ---- w2 transpose: f32 [F][H] -> bf16 [H][F], two 64x64 tiles per block ----
    const int half = tid >> 8;          // 0 or 1
    const int t2 = tid & 255;
    unsigned short* tile = (unsigned short*)(lds + half * 10240);
    const int tt = (id - G1) * 2 + half;
    const int e = tt >> 10, rem = tt & 1023;
    const int R = FD, C = HD;
    const int r0 = (rem >> 4) << 6, c0 = (rem & 15) << 6;
    const float* src = w2 + (size_t)e * R * C;
    unsigned short* dst = w2t + (size_t)e * R * C;
    {
      const int r = t2 >> 2, cg = (t2 & 3) * 16;
      #pragma unroll
      for (int m = 0; m < 4; ++m) {
        float4 v = *(const float4*)(src + (size_t)(r0 + r) * C + c0 + cg + 4 * m);
        s16x4 pv;
        pv[0] = (short)f2bf(v.x); pv[1] = (short)f2bf(v.y);
        pv[2] = (short)f2bf(v.z); pv[3] = (short)f2bf(v.w);
        *(s16x4*)&tile[r * 80 + cg + 4 * m] = pv;
      }
    }
    __syncthreads();
    {
      const int c = t2 >> 2, rg = (t2 & 3) * 16;
      bf16x8 v0, v1;
      #pragma unroll
      for (int j = 0; j < 8; ++j) v0[j] = (short)tile[(rg + j) * 80 + c];
      #pragma unroll
      for (int j = 0; j < 8; ++j) v1[j] = (short)tile[(rg + 8 + j) * 80 + c];
      unsigned short* dp = dst + (size_t)(c0 + c) * R + r0 + rg;
      *(bf16x8*)dp = v0;
      *(bf16x8*)(dp + 8) = v1;
    }
    return;
  }
  const int xcd = id & 7, l = id >> 3;      // l in 0..143
  const int ntr = offs[8] >> 8;             // valid row-tiles (<= 72)
  const int nj = ntr * 16;                  // valid jobs (<= 1152)
  const int q = nj >> 3, r8 = nj & 7;
  const int cnt = q + (xcd < r8 ? 1 : 0);
  if (l >= cnt) return;
  const int start = (xcd < r8) ? xcd * (q + 1) : r8 * (q + 1) + (xcd - r8) * q;
  const int g = start + l;
  const int rt = g >> 4, nb = g & 15;
  const int row0 = rt * 256;
  int e = 0;
  #pragma unroll
  for (int i = 1; i < 8; ++i) if (row0 >= offs[i]) e = i;
  const int n0 = nb * 256;
  const int lane = tid & 63;
  const int wid = tid >> 6;
  const int wm = wid >> 2, wn = wid & 3;

  const int rl = tid >> 3;
  const int cbs = ((tid & 7) << 4) ^ ((rl & 7) << 4);
  const char* pA[2][2];
  #pragma unroll
  for (int h = 0; h < 2; ++h)
    #pragma unroll
    for (int l2 = 0; l2 < 2; ++l2) {
      int tok = rowmap[row0 + h * 128 + l2 * 64 + rl] >> 1;
      pA[h][l2] = (const char*)xbf + (size_t)tok * 2048 + cbs;
    }
  const char* pB00 = (const char*)w1t + (size_t)e * ((size_t)FD * HD * 2) +
                     (size_t)(n0 + rl) * 2048 + cbs;
  const int stw = wid * 1024;

#define STA1(buf, h, kt) do { \
  gld_lds16(pA[h][0] + (size_t)(kt) * 128, lds + (buf) * 65536 + (h) * 16384 + stw); \
  gld_lds16(pA[h][1] + (size_t)(kt) * 128, lds + (buf) * 65536 + (h) * 16384 + 8192 + stw); } while (0)
#define STB1(buf, h, kt) do { \
  gld_lds16(pB00 + (size_t)(h) * 128 * 2048 + (size_t)(kt) * 128, \
            lds + (buf) * 65536 + 32768 + (h) * 16384 + stw); \
  gld_lds16(pB00 + ((size_t)(h) * 128 + 64) * 2048 + (size_t)(kt) * 128, \
            lds + (buf) * 65536 + 32768 + (h) * 16384 + 8192 + stw); } while (0)

  FRAG_OFFSETS256();
  const int wmOff = wm * 16384;
  const int wnOff = 32768 + (wn >> 1) * 16384;

  f32x4 acc[8][4];
  #pragma unroll
  for (int a = 0; a < 8; ++a)
    #pragma unroll
    for (int b = 0; b < 4; ++b) acc[a][b] = (f32x4){0.f, 0.f, 0.f, 0.f};
  bf16x8 af[4][2], b0r[2][2], b1r[2][2];

  STA1(0, 0, 0); STA1(0, 1, 0); STB1(0, 0, 0); STB1(0, 1, 0);
  STB1(1, 0, 1); STB1(1, 1, 1);
  asm volatile("s_waitcnt vmcnt(4)" ::: "memory");
  __builtin_amdgcn_sched_barrier(0);
  __builtin_amdgcn_s_barrier();
  __builtin_amdgcn_sched_barrier(0);

  #pragma unroll 1
  for (int i = 0; i < NKT1 / 2; ++i) {
    const int k1 = 2 * i + 1, k2 = 2 * i + 2, k3 = 2 * i + 3;
    RDA(0, 0); RDB(0, 0, b0r); STA1(1, 0, k1); SYNC_PRE(); MMA(0, 0, b0r); SYNC_POST();
    RDB(0, 1, b1r);            STA1(1, 1, k1); SYNC_PRE(); MMA(0, 1, b1r); SYNC_POST();
    RDA(0, 1);                 STB1(0, 0, k2); SYNC_PRE(); MMA(1, 1, b1r); SYNC_POST();
                               STB1(0, 1, k2); SYNC_PRE(); MMA(1, 0, b0r); SYNC_POST_VM();
    RDA(1, 0); RDB(1, 0, b0r); STA1(0, 0, k2); SYNC_PRE(); MMA(0, 0, b0r); SYNC_POST();
    RDB(1, 1, b1r);            STA1(0, 1, k2); SYNC_PRE(); MMA(0, 1, b1r); SYNC_POST();
    RDA(1, 1);                 STB1(1, 0, k3); SYNC_PRE(); MMA(1, 1, b1r); SYNC_POST();
                               STB1(1, 1, k3); SYNC_PRE(); MMA(1, 0, b0r); SYNC_POST_VM();
  }

  asm volatile("s_waitcnt vmcnt(0)" ::: "memory");
  __builtin_amdgcn_sched_barrier(0);
  __syncthreads();
  // bias + relu -> LDS bf16 [256][512B] swizzled -> coalesced store
  #pragma unroll
  for (int na = 0; na < 4; ++na) {
    int c = wn * 64 + (na >> 1) * 32 + (na & 1) * 16 + (lane & 15);
    float bias = b1[(size_t)e * FD + n0 + c];
    #pragma unroll
    for (int ma = 0; ma < 8; ++ma) {
      #pragma unroll
      for (int j2 = 0; j2 < 4; ++j2) {
        int r = wm * 128 + (ma >> 2) * 64 + (ma & 3) * 16 + ((lane >> 4) << 2) + j2;
        float v = fmaxf(acc[ma][na][j2] + bias, 0.f);
        *(unsigned short*)(lds + r * 512 + ((c * 2) ^ ((r & 7) << 4))) = f2bf(v);
      }
    }
  }
  __syncthreads();
  #pragma unroll
  for (int s = 0; s < 16; ++s) {
    int flat = s * 512 + tid;
    int r = flat >> 5, ch = flat & 31;
    bf16x8 v = *(const bf16x8*)(lds + r * 512 + ((ch * 16) ^ ((r & 7) << 4)));
    *(bf16x8*)((char*)hbuf + (size_t)(row0 + r) * 8192 + (size_t)n0 * 2 + ch * 16) = v;
  }
#undef STA1
#undef STB1
}

// ---------------- GEMM2: fulls -> out2; tail quarter-K jobs -> psplit ----------------
__global__ __launch_bounds__(512, 2) void k_gemm2(const unsigned short* __restrict__ hbuf,
                                                  const unsigned short* __restrict__ w2t,
                                                  const float* __restrict__ b2,
                                                  const int* __restrict__ rowmap,
                                                  const float* __restrict__ roww,
                                                  const int* __restrict__ offs,
                                                  float* __restrict__ out2,
                                                  float* __restrict__ psplit) {
  __shared__ char lds[131072];
  const int id = blockIdx.x;
  int bx, by, kt0, niter, jj = -1;
  if (id < 256) {
    const int sid = (id & 7) * 32 + (id >> 3);   // bijective over 256
    bx = sid & 3; by = sid >> 2;                 // by < 64: always valid
    kt0 = 0; niter = 32;
  } else {
    const int jid = id - 256;
    const int q = (jid & 7) * 16 + (jid >> 3);   // bijective over 128
    const int t = 256 + (q >> 2);
    const int nT2 = (offs[8] >> 8) * 4;
    if (t >= nT2) return;
    bx = t & 3; by = t >> 2;
    kt0 = (q & 3) * 16; niter = 8;
    jj = q;
  }
  const int row0 = by * 256;
  int e = 0;
  #pragma unroll
  for (int i = 1; i < 8; ++i) if (row0 >= offs[i]) e = i;
  const int n0 = bx * 256;
  const int tid = threadIdx.x;
  const int lane = tid & 63;
  const int wid = tid >> 6;
  const int wm = wid >> 2, wn = wid & 3;

  const int rl = tid >> 3;
  const int cbs = ((tid & 7) << 4) ^ ((rl & 7) << 4);
  const char* pA00 = (const char*)hbuf + (size_t)(row0 + rl) * 8192 + cbs;
  const char* pB00 = (const char*)w2t + (size_t)e * ((size_t)HD * FD * 2) +
                     (size_t)(n0 + rl) * 8192 + cbs;
  const int stw = wid * 1024;

#define STA2(buf, h, kt) do { \
  gld_lds16(pA00 + (size_t)(h) * 128 * 8192 + (size_t)(kt) * 128, \
            lds + (buf) * 65536 + (h) * 16384 + stw); \
  gld_lds16(pA00 + ((size_t)(h) * 128 + 64) * 8192 + (size_t)(kt) * 128, \
            lds + (buf) * 65536 + (h) * 16384 + 8192 + stw); } while (0)
#define STB2(buf, h, kt) do { \
  gld_lds16(pB00 + (size_t)(h) * 128 * 8192 + (size_t)(kt) * 128, \
            lds + (buf) * 65536 + 32768 + (h) * 16384 + stw); \
  gld_lds16(pB00 + ((size_t)(h) * 128 + 64) * 8192 + (size_t)(kt) * 128, \
            lds + (buf) * 65536 + 32768 + (h) * 16384 + 8192 + stw); } while (0)

  FRAG_OFFSETS256();
  const int wmOff = wm * 16384;
  const int wnOff = 32768 + (wn >> 1) * 16384;

  f32x4 acc[8][4];
  #pragma unroll
  for (int a = 0; a < 8; ++a)
    #pragma unroll
    for (int b = 0; b < 4; ++b) acc[a][b] = (f32x4){0.f, 0.f, 0.f, 0.f};
  bf16x8 af[4][2], b0r[2][2], b1r[2][2];

  STA2(0, 0, kt0); STA2(0, 1, kt0); STB2(0, 0, kt0); STB2(0, 1, kt0);
  STB2(1, 0, kt0 + 1); STB2(1, 1, kt0 + 1);
  asm volatile("s_waitcnt vmcnt(4)" ::: "memory");
  __builtin_amdgcn_sched_barrier(0);
  __builtin_amdgcn_s_barrier();
  __builtin_amdgcn_sched_barrier(0);

  #pragma unroll 1
  for (int i = 0; i < niter; ++i) {
    const int k1 = kt0 + 2 * i + 1, k2 = kt0 + 2 * i + 2, k3 = kt0 + 2 * i + 3;
    RDA(0, 0); RDB(0, 0, b0r); STA2(1, 0, k1); SYNC_PRE(); MMA(0, 0, b0r); SYNC_POST();
    RDB(0, 1, b1r);            STA2(1, 1, k1); SYNC_PRE(); MMA(0, 1, b1r); SYNC_POST();
    RDA(0, 1);                 STB2(0, 0, k2); SYNC_PRE(); MMA(1, 1, b1r); SYNC_POST();
                               STB2(0, 1, k2); SYNC_PRE(); MMA(1, 0, b0r); SYNC_POST_VM();
    RDA(1, 0); RDB(1, 0, b0r); STA2(0, 0, k2); SYNC_PRE(); MMA(0, 0, b0r); SYNC_POST();
    RDB(1, 1, b1r);            STA2(0, 1, k2); SYNC_PRE(); MMA(0, 1, b1r); SYNC_POST();
    RDA(1, 1);                 STB2(1, 0, k3); SYNC_PRE(); MMA(1, 1, b1r); SYNC_POST();
                               STB2(1, 1, k3); SYNC_PRE(); MMA(1, 0, b0r); SYNC_POST_VM();
  }

  asm volatile("s_waitcnt vmcnt(0)" ::: "memory");
  __builtin_amdgcn_sched_barrier(0);
  if (jj < 0) {
    // full tile: bias + weight scale -> out2 slot rows (padding -> trash row)
    #pragma unroll
    for (int ma = 0; ma < 8; ++ma) {
      #pragma unroll
      for (int j2 = 0; j2 < 4; ++j2) {
        int r = wm * 128 + (ma >> 2) * 64 + (ma & 3) * 16 + ((lane >> 4) << 2) + j2;
        int rm = rowmap[row0 + r];
        float wr = roww[row0 + r];
        float* orow = out2 + (size_t)rm * 1024 + n0;
        #pragma unroll
        for (int na = 0; na < 4; ++na) {
          int c = wn * 64 + (na >> 1) * 32 + (na & 1) * 16 + (lane & 15);
          orow[c] = (acc[ma][na][j2] + b2[(size_t)e * HD + n0 + c]) * wr;
        }
      }
    }
  } else {
    // quarter job: raw partial sums -> psplit[jj][256][256]
    float* ps = psplit + (size_t)jj * 65536;
    #pragma unroll
    for (int ma = 0; ma < 8; ++ma) {
      #pragma unroll
      for (int j2 = 0; j2 < 4; ++j2) {
        int r = wm * 128 + (ma >> 2) * 64 + (ma & 3) * 16 + ((lane >> 4) << 2) + j2;
        #pragma unroll
        for (int na = 0; na < 4; ++na) {
          int c = wn * 64 + (na >> 1) * 32 + (na & 1) * 16 + (lane & 15);
          ps[r * 256 + c] = acc[ma][na][j2];
        }
      }
    }
  }
#undef STA2
#undef STB2
}

// ---------------- fix2: combine quarter partials of tail tiles into out2 ----------------
__global__ __launch_bounds__(512) void k_fix2(const float* __restrict__ psplit,
                                              const int* __restrict__ offs,
                                              const float* __restrict__ b2,
                                              const int* __restrict__ rowmap,
                                              const float* __restrict__ roww,
                                              float* __restrict__ out2) {
  const int nT2 = (offs[8] >> 8) * 4;
  const int t = 256 + blockIdx.x;
  if (t >= nT2) return;
  const int by = t >> 2, bx = t & 3;
  const int row0 = by * 256, n0 = bx * 256;
  int e = 0;
  #pragma unroll
  for (int i = 1; i < 8; ++i) if (row0 >= offs[i]) e = i;
  const float* ps = psplit + (size_t)blockIdx.x * 4 * 65536;
  const int cg = (threadIdx.x & 63) * 4;
  const int r0t = threadIdx.x >> 6;
  float4 bb = *(const float4*)(b2 + (size_t)e * HD + n0 + cg);
  for (int rr = 0; rr < 32; ++rr) {
    int r = rr * 8 + r0t;
    int rm = rowmap[row0 + r];
    float wr = roww[row0 + r];
    float4 s0 = *(const float4*)(ps + 0 * 65536 + r * 256 + cg);
    float4 s1 = *(const float4*)(ps + 1 * 65536 + r * 256 + cg);
    float4 s2 = *(const float4*)(ps + 2 * 65536 + r * 256 + cg);
    float4 s3 = *(const float4*)(ps + 3 * 65536 + r * 256 + cg);
    float4 o;
    o.x = wr * (s0.x + s1.x + s2.x + s3.x + bb.x);
    o.y = wr * (s0.y + s1.y + s2.y + s3.y + bb.y);
    o.z = wr * (s0.z + s1.z + s2.z + s3.z + bb.z);
    o.w = wr * (s0.w + s1.w + s2.w + s3.w + bb.w);
    *(float4*)(out2 + (size_t)rm * 1024 + n0 + cg) = o;
  }
}

// ---------------- combine: out[t] = out2[2t] + out2[2t+1] ----------------
__global__ __launch_bounds__(256) void k_combine(const float* __restrict__ out2,
                                                 float* __restrict__ out) {
  const int t = blockIdx.x;
  const int i = threadIdx.x * 4;
  float4 a = *(const float4*)(out2 + (size_t)(2 * t) * 1024 + i);
  float4 b = *(const float4*)(out2 + (size_t)(2 * t + 1) * 1024 + i);
  float4 r;
  r.x = a.x + b.x; r.y = a.y + b.y; r.z = a.z + b.z; r.w = a.w + b.w;
  *(float4*)(out + (size_t)t * 1024 + i) = r;
}

extern "C" void kernel_launch(void* const* d_in, const int* in_sizes, int n_in,
                              void* d_out, int out_size, void* d_ws, size_t ws_size,
                              hipStream_t stream) {
  const float* x = (const float*)d_in[0];
  const float* gw = (const float*)d_in[1];
  const float* w1 = (const float*)d_in[2];
  const float* b1 = (const float*)d_in[3];
  const float* w2 = (const float*)d_in[4];
  const float* b2 = (const float*)d_in[5];
  float* out = (float*)d_out;

  char* ws = (char*)d_ws;
  size_t o = 0;
  unsigned short* w2t = (unsigned short*)(ws + o); o += (size_t)NE * HD * FD * 2;   // 64 MiB
  unsigned short* hbuf = (unsigned short*)(ws + o); o += (size_t)RALLOC * FD * 2;   // 144 MiB
  unsigned short* w1t = (unsigned short*)(ws + o);
  size_t w1t_off = o; o += (size_t)NE * FD * HD * 2;                                // 64 MiB
  unsigned short* xbf = (unsigned short*)(ws + o); o += (size_t)T_TOK * HD * 2;     // 16 MiB
  int* rowmap = (int*)(ws + o); o += (size_t)RALLOC * 4;
  float* roww = (float*)(ws + o); o += (size_t)RALLOC * 4;
  int* toke = (int*)(ws + o); o += (size_t)T_TOK * 2 * 4;
  float* tokw = (float*)(ws + o); o += (size_t)T_TOK * 2 * 4;
  double* part = (double*)(ws + o); o += (size_t)GATE_BLOCKS * 8 * 8;
  int* counts8 = (int*)(ws + o); o += (size_t)GATE_BLOCKS * 8 * 4;
  int* ctrl = (int*)(ws + o); o += 1024;
  int* offs = ctrl;            // 9 ints
  int* cursors = ctrl + 64;    // 8 cursors, stride 16 ints
  float* psplit = (float*)(ws + o); o += (size_t)128 * 65536 * 4;                   // 32 MiB
  // out2 aliases [w1t ∪ xbf] (both dead after gemm1): 64.004 MiB < 80 MiB
  float* out2 = (float*)(ws + w1t_off);

  k_prep1<<<TP1_BLOCKS + GATE_BLOCKS, 512, 0, stream>>>(w1, w1t, x, gw, toke, tokw,
                                                        counts8, part, xbf);
  k_scan<<<1, 256, 0, stream>>>(counts8, offs, cursors, part, out + (size_t)T_TOK * HD,
                                rowmap, roww);
  k_scatter<<<T_TOK / 256, 256, 0, stream>>>(toke, tokw, cursors, rowmap, roww);
  k_gemm1<<<G1 + 4096, 512, 0, stream>>>(xbf, w1t, b1, rowmap, offs, hbuf, w2, w2t);
  k_gemm2<<<G2, 512, 0, stream>>>(hbuf, w2t, b2, rowmap, roww, offs, out2, psplit);
  k_fix2<<<32, 512, 0, stream>>>(psplit, offs, b2, rowmap, roww, out2);
  k_combine<<<T_TOK, 256, 0, stream>>>(out2, out);
}